// Round 11
// baseline (355.858 us; speedup 1.0000x reference)
//
#include <hip/hip_runtime.h>
#include <hip/hip_bf16.h>

// Problem constants: N=50000, E=1600000, D=3, IN=32, OUT=32, KS=4, K=64, S=8
// Deterministic sort structure, zero scattered global atomics, NT-hinted
// streams so the 3.2 MB feature table stays L2-resident for the MFMA gather.
// (Round-9 fix: __builtin_nontemporal_* requires clang ext_vector types, not
// HIP_vector_type uint2/uint4 — swapped to u32x2/u32x4.)
//   group_rank: 128 edge-groups; full 50K-row LDS histogram (2 rows/u32,
//       100 KB); LDS atomic return = lrank[e]; counts -> gcnt[g][row].
//   prep: pack W/f to bf16 + per-chunk 27-bin bucket histogram.
//   deg_total: degi[row] = sum_g gcnt[g][row].
//   scan_combo: blk0 scans bh[27][NCHUNK]; blk1 scans degi -> rstart.
//   group_base: gcnt[g][row] = rstart[row] + prefix_g (in place).
//   bucket_scatter: counting sort; edata PACKED to 8 B (frac unorm16 x3 +
//       col u16); rpos = gcnt[e/GSZ][row] + lrank[e]. LDS atomics only.
//   edge_mfma_nw: per-bucket MFMA, swapped operands; W frags staged in LDS
//       (shared by the block's 4 waves -> lower VGPR, more waves/SIMD);
//       NT stream loads/stores; one dwordx4 msg store at row-sorted slot.
//   gather_out: per node, contiguous [rstart[n],rstart[n+1]) coalesced sum.
#define NN 50000
#define EE 1600000
#define BPB 96               // blocks per bucket in edge_mfma_nw
#define CH 1024              // edges per chunk (bucket hist/scatter)
#define NCHUNK ((EE + CH - 1) / CH)   // 1563
#define GG 128               // rank groups
#define GSZ (EE / GG)        // 12500 edges per group (exact)

typedef __attribute__((ext_vector_type(8))) short    s16x8;   // 8 bf16 (4 VGPRs)
typedef __attribute__((ext_vector_type(4))) float    f32x4;   // MFMA C/D frag
typedef __attribute__((ext_vector_type(2))) unsigned u32x2;   // NT-able 8 B
typedef __attribute__((ext_vector_type(4))) unsigned u32x4;   // NT-able 16 B

static __device__ __forceinline__ short f2bs(float x) {
  __hip_bfloat16 h = __float2bfloat16(x);
  short s; __builtin_memcpy(&s, &h, 2); return s;
}

__constant__ int kOffs[8] = {0, 1, 4, 5, 16, 17, 20, 21};

// ---------------------------------------------------------------------------
// group_rank: block g owns edges [g*GSZ,(g+1)*GSZ). Full-row histogram in LDS
// (2 rows/u32; halves never carry since per-half count <= 12500 < 65536).
// LDS atomic RETURN = within-(group,row) rank -> lrank[e].
// ---------------------------------------------------------------------------
__global__ __launch_bounds__(256) void group_rank(const int* __restrict__ ei,
                                                  unsigned short* __restrict__ lrank,
                                                  int* __restrict__ gcnt) {
  __shared__ unsigned lh32[NN / 2];                // 25000 words = 100 KB
  for (int j = threadIdx.x; j < NN / 2; j += 256) lh32[j] = 0;
  __syncthreads();
  const int g  = blockIdx.x;
  const int e0 = g * GSZ;
  for (int i = threadIdx.x; i < GSZ; i += 256) {
    int e = e0 + i;
    int row = __builtin_nontemporal_load(ei + e);
    unsigned add = (row & 1) ? 0x10000u : 1u;
    unsigned ret = atomicAdd(&lh32[row >> 1], add);
    unsigned r = (row & 1) ? (ret >> 16) : (ret & 0xFFFFu);
    __builtin_nontemporal_store((unsigned short)r, lrank + e);
  }
  __syncthreads();
  for (int j = threadIdx.x; j < NN / 2; j += 256) {
    unsigned u = lh32[j];
    __builtin_nontemporal_store((int)(u & 0xFFFFu), gcnt + (size_t)g * NN + 2 * j);
    __builtin_nontemporal_store((int)(u >> 16),     gcnt + (size_t)g * NN + 2 * j + 1);
  }
}

// ---------------------------------------------------------------------------
// prep (fused): blocks [0,32) conv_w ; [32,160) pack_f ; [160,160+NCHUNK)
// per-chunk 27-bin bucket histogram (LDS-only atomics).
// conv_w frag layout: (tile t=kmat*2+oh, lane l, j) =
//   W[kmat][(l>>4)*8+j][oh*16+(l&15)] — read as A-frag it is W^T.
// Wb/fbh stored with PLAIN stores (they are re-read by edge_mfma — keep in L2).
// ---------------------------------------------------------------------------
#define PREP_BLOCKS (160 + NCHUNK)
__global__ __launch_bounds__(256) void prep(const float* __restrict__ W,
                                            const float* __restrict__ f,
                                            const float* __restrict__ pseudo,
                                            short* __restrict__ Wb,
                                            short* __restrict__ fbh,
                                            int* __restrict__ bh) {
  const int b = blockIdx.x;
  if (b < 32) {
    int tid = b * 256 + threadIdx.x;               // 8192 threads, one frag each
    int t = tid >> 6, l = tid & 63;
    int c = t * 16 + (l & 15);
    int k0 = (l >> 4) * 8;
    s16x8 frag;
#pragma unroll
    for (int j = 0; j < 8; ++j)
      frag[j] = f2bs(W[(c >> 5) * 1024 + (k0 + j) * 32 + (c & 31)]);
    ((s16x8*)Wb)[tid] = frag;
  } else if (b < 160) {
    for (int tid = (b - 32) * 256 + threadIdx.x; tid < NN * 32 / 8; tid += 128 * 256) {
      const f32x4* fp = (const f32x4*)f + (size_t)tid * 2;
      f32x4 a = fp[0], c = fp[1];
      s16x8 o;
#pragma unroll
      for (int j = 0; j < 4; ++j) { o[j] = f2bs(a[j]); o[4 + j] = f2bs(c[j]); }
      ((s16x8*)fbh)[tid] = o;
    }
  } else {
    __shared__ int lh[27];
    if (threadIdx.x < 27) lh[threadIdx.x] = 0;
    __syncthreads();
    const int c  = b - 160;                        // chunk id
    const int e0 = c * CH;
#pragma unroll
    for (int i = 0; i < CH / 256; ++i) {
      int e = e0 + i * 256 + threadIdx.x;
      if (e < EE) {
        float v0 = __builtin_nontemporal_load(pseudo + e * 3 + 0) * 3.0f;
        float v1 = __builtin_nontemporal_load(pseudo + e * 3 + 1) * 3.0f;
        float v2 = __builtin_nontemporal_load(pseudo + e * 3 + 2) * 3.0f;
        int b0 = (int)fminf(fmaxf(floorf(v0), 0.0f), 2.0f);
        int b1 = (int)fminf(fmaxf(floorf(v1), 0.0f), 2.0f);
        int b2 = (int)fminf(fmaxf(floorf(v2), 0.0f), 2.0f);
        atomicAdd(&lh[b0 + 3 * b1 + 9 * b2], 1);
      }
    }
    __syncthreads();
    if (threadIdx.x < 27) bh[threadIdx.x * NCHUNK + c] = lh[threadIdx.x];
  }
}

// ---------------------------------------------------------------------------
// deg_total: degi[row] = sum over groups of gcnt[g][row] (coalesced per g).
// ---------------------------------------------------------------------------
__global__ __launch_bounds__(256) void deg_total(const int* __restrict__ gcnt,
                                                 int* __restrict__ degi) {
  int row = blockIdx.x * 256 + threadIdx.x;
  if (row >= NN) return;
  int s = 0;
#pragma unroll 8
  for (int g = 0; g < GG; ++g) s += __builtin_nontemporal_load(gcnt + (size_t)g * NN + row);
  degi[row] = s;
}

// ---------------------------------------------------------------------------
// scan_combo (grid=2, 1024 threads):
//   block 0: in-place exclusive scan of bh[27*NCHUNK] (bin-major flat), then
//            bstart[q] = bh[q*NCHUNK] (bstart[27] = EE).
//   block 1: exclusive scan of degi[50000] -> rstart[0..NN].
// ---------------------------------------------------------------------------
__global__ __launch_bounds__(1024) void scan_combo(int* __restrict__ bh,
                                                   const int* __restrict__ degi,
                                                   int* __restrict__ bstart,
                                                   int* __restrict__ rstart) {
  __shared__ int carry;
  __shared__ int tot;
  __shared__ int wsum[16];
  const int lane = threadIdx.x & 63;
  const int wid  = threadIdx.x >> 6;
  if (threadIdx.x == 0) carry = 0;
  __syncthreads();
  if (blockIdx.x == 0) {
    const int L = 27 * NCHUNK;
    for (int c0 = 0; c0 < L; c0 += 1024) {
      int i = c0 + threadIdx.x;
      int v = (i < L) ? bh[i] : 0;
      int x = v;
#pragma unroll
      for (int d = 1; d < 64; d <<= 1) {
        int y = __shfl_up(x, d, 64);
        if (lane >= d) x += y;
      }
      if (lane == 63) wsum[wid] = x;
      __syncthreads();
      if (threadIdx.x == 0) {
        int run = 0;
#pragma unroll
        for (int w = 0; w < 16; ++w) { int t = wsum[w]; wsum[w] = run; run += t; }
        tot = run;
      }
      __syncthreads();
      int excl = carry + wsum[wid] + (x - v);
      if (i < L) bh[i] = excl;
      __syncthreads();
      if (threadIdx.x == 0) carry += tot;
      __syncthreads();
    }
    if (threadIdx.x < 27) bstart[threadIdx.x] = bh[threadIdx.x * NCHUNK];
    if (threadIdx.x == 27) bstart[27] = EE;
  } else {
    for (int c0 = 0; c0 < NN; c0 += 1024) {
      int i = c0 + threadIdx.x;
      int v = (i < NN) ? degi[i] : 0;
      int x = v;
#pragma unroll
      for (int d = 1; d < 64; d <<= 1) {
        int y = __shfl_up(x, d, 64);
        if (lane >= d) x += y;
      }
      if (lane == 63) wsum[wid] = x;
      __syncthreads();
      if (threadIdx.x == 0) {
        int run = 0;
#pragma unroll
        for (int w = 0; w < 16; ++w) { int t = wsum[w]; wsum[w] = run; run += t; }
        tot = run;
      }
      __syncthreads();
      int excl = carry + wsum[wid] + (x - v);
      if (i < NN) rstart[i] = excl;
      __syncthreads();
      if (threadIdx.x == 0) carry += tot;
      __syncthreads();
    }
    if (threadIdx.x == 0) rstart[NN] = carry;      // == EE
  }
}

// ---------------------------------------------------------------------------
// group_base: in-place gcnt[g][row] = rstart[row] + prefix over g'<g.
// Loads batched 8-wide so the 128-step chain isn't latency-serialized.
// ---------------------------------------------------------------------------
__global__ __launch_bounds__(256) void group_base(int* __restrict__ gcnt,
                                                  const int* __restrict__ rstart) {
  int row = blockIdx.x * 256 + threadIdx.x;
  if (row >= NN) return;
  int run = rstart[row];
  for (int g0 = 0; g0 < GG; g0 += 8) {
    int t[8];
#pragma unroll
    for (int j = 0; j < 8; ++j) t[j] = gcnt[(size_t)(g0 + j) * NN + row];
#pragma unroll
    for (int j = 0; j < 8; ++j) {
      int v = t[j];
      gcnt[(size_t)(g0 + j) * NN + row] = run;
      run += v;
    }
  }
}

// ---------------------------------------------------------------------------
// Counting-sort scatter, ZERO global atomics. 1 block = 1 chunk (same edge
// partitioning as prep's hist). Rank within (chunk,bin) via LDS atomics;
// base = pre-scanned bh[q*NCHUNK+c].
// edata PACKED 8 B: x = f0q | f1q<<16, y = f2q | col<<16  (frac unorm16,
// quantization err ~2e-5 in spline weights — far below bf16 noise).
// rpos_arr[pos] = gcnt[e/GSZ][row] + lrank[e]   (row-sorted message slot).
// ---------------------------------------------------------------------------
static __device__ __forceinline__ unsigned q16(float fr) {
  return min((unsigned)(fr * 65536.0f), 65535u);
}
__global__ __launch_bounds__(256) void bucket_scatter(const float* __restrict__ pseudo,
                                                      const int* __restrict__ ei,
                                                      const unsigned short* __restrict__ lrank,
                                                      const int* __restrict__ gcnt,
                                                      const int* __restrict__ bh,
                                                      u32x2* __restrict__ edata,
                                                      int* __restrict__ rpos_arr) {
  __shared__ int lh[27];
  __shared__ int bb[27];
  if (threadIdx.x < 27) {
    lh[threadIdx.x] = 0;
    bb[threadIdx.x] = bh[threadIdx.x * NCHUNK + blockIdx.x];
  }
  __syncthreads();
  const int e0 = blockIdx.x * CH;
#pragma unroll
  for (int i = 0; i < CH / 256; ++i) {
    int e = e0 + i * 256 + threadIdx.x;
    if (e < EE) {
      float v0 = __builtin_nontemporal_load(pseudo + e * 3 + 0) * 3.0f;
      float v1 = __builtin_nontemporal_load(pseudo + e * 3 + 1) * 3.0f;
      float v2 = __builtin_nontemporal_load(pseudo + e * 3 + 2) * 3.0f;
      float fb0 = fmaxf(fminf(floorf(v0), 2.0f), 0.0f);
      float fb1 = fmaxf(fminf(floorf(v1), 2.0f), 0.0f);
      float fb2 = fmaxf(fminf(floorf(v2), 2.0f), 0.0f);
      int q = (int)fb0 + 3 * (int)fb1 + 9 * (int)fb2;
      int rk = atomicAdd(&lh[q], 1);
      int pos = bb[q] + rk;
      int row = __builtin_nontemporal_load(ei + e);
      int col = __builtin_nontemporal_load(ei + EE + e);
      int ge  = e / GSZ;
      u32x2 pk;
      pk.x = q16(v0 - fb0) | (q16(v1 - fb1) << 16);
      pk.y = q16(v2 - fb2) | ((unsigned)col << 16);
      __builtin_nontemporal_store(pk, edata + pos);
      int rp = gcnt[(size_t)ge * NN + row] + (int)__builtin_nontemporal_load(lrank + e);
      __builtin_nontemporal_store(rp, rpos_arr + pos);
    }
  }
}

// ---------------------------------------------------------------------------
// Bucketed MFMA, atomic-free, SWAPPED OPERANDS, W frags staged in LDS.
// Per group of 16 edges: D = mfma(A=W^T tile, B=f^T (fbh frag), 0)
//   -> D[row=(l>>4)*4+r = o-channel][col=l&15 = edge]  (m89 layout).
// Lane l owns edge m=l&15; weights + rpos lane-local (no cross-lane ops).
// All stream accesses NT so fbh (3.2 MB) stays L2-resident for the gather.
// Store: ONE dwordx4 per lane: msg4[rp*4+kq] = {pk(o,o+16)}_{r=0..3}.
// ---------------------------------------------------------------------------
__global__ __launch_bounds__(256) void edge_mfma_nw(const u32x2* __restrict__ edata,
                                                    const int* __restrict__ rpos_arr,
                                                    const short* __restrict__ fbh,
                                                    const short* __restrict__ Wb,
                                                    const int* __restrict__ bstart,
                                                    u32x4* __restrict__ msg4) {
  const int q   = blockIdx.x / BPB;
  const int sub = blockIdx.x % BPB;
  const int l   = threadIdx.x & 63;
  const int wid = threadIdx.x >> 6;

  const int start = bstart[q];
  const int end   = bstart[q + 1];
  const int nE    = end - start;
  if (nE <= 0) return;                             // uniform — no barrier yet
  const int ngroups = (nE + 15) >> 4;

  const int b0 = q % 3, b1 = (q / 3) % 3, b2 = q / 9;
  const int base = b0 + 4 * b1 + 16 * b2;

  // Stage the bucket's 16 W fragments (8 s-matrices x 2 col-tiles) in LDS:
  // 16 frags x 64 lanes x 16 B = 16 KB, shared by all 4 waves.
  __shared__ s16x8 wlds[16 * 64];
  for (int i = threadIdx.x; i < 16 * 64; i += 256) {
    int fr = i >> 6, l2 = i & 63;
    int s = fr >> 1, oh = fr & 1;
    int kmat = base + (s & 1) + ((s >> 1) & 1) * 4 + (s >> 2) * 16;
    wlds[i] = ((const s16x8*)Wb)[(kmat * 2 + oh) * 64 + l2];
  }
  __syncthreads();

  const int m   = l & 15;         // edge-in-group OWNED by this lane
  const int kq  = l >> 4;         // B k-chunk / D o-quarter
  const int stride = BPB * 4;

  int g = sub * 4 + wid;
  if (g >= ngroups) return;

  const float inv16 = 1.0f / 65536.0f;

  int idx = start + g * 16 + m;
  int cidx = idx < end ? idx : start;
  u32x2 ed = __builtin_nontemporal_load(edata + cidx);
  int   rp = __builtin_nontemporal_load(rpos_arr + cidx);
  s16x8 af = ((const s16x8*)fbh)[(size_t)(ed.y >> 16) * 4 + kq];

  while (true) {
    const int gn = g + stride;
    const bool more = gn < ngroups;
    int idxn = start + gn * 16 + m;
    int cidxn = (more && idxn < end) ? idxn : start;
    u32x2 edn = __builtin_nontemporal_load(edata + cidxn);   // prefetch
    int   rpn = __builtin_nontemporal_load(rpos_arr + cidxn);

    // spline weights of this lane's OWN edge (unorm16 fracs)
    float f0 = (float)(ed.x & 0xFFFFu) * inv16;
    float f1 = (float)(ed.x >> 16)     * inv16;
    float f2 = (float)(ed.y & 0xFFFFu) * inv16;
    float g0 = 1.0f - f0, g1c = 1.0f - f1, g2c = 1.0f - f2;
    float w8[8];
    w8[0] = g0 * g1c * g2c; w8[1] = f0 * g1c * g2c;
    w8[2] = g0 * f1 * g2c;  w8[3] = f0 * f1 * g2c;
    w8[4] = g0 * g1c * f2;  w8[5] = f0 * g1c * f2;
    w8[6] = g0 * f1 * f2;   w8[7] = f0 * f1 * f2;

    // prefetch next B-frag (hides fbh gather under MFMA+store)
    s16x8 afn = ((const s16x8*)fbh)[(size_t)(edn.y >> 16) * 4 + kq];

    f32x4 acc0 = {0.f, 0.f, 0.f, 0.f}, acc1 = {0.f, 0.f, 0.f, 0.f};
#pragma unroll
    for (int s = 0; s < 8; ++s) {
      s16x8 bf0 = wlds[(s * 2 + 0) * 64 + l];
      s16x8 bf1 = wlds[(s * 2 + 1) * 64 + l];
      f32x4 d0 = __builtin_amdgcn_mfma_f32_16x16x32_bf16(bf0, af,
                   (f32x4){0.f, 0.f, 0.f, 0.f}, 0, 0, 0);   // o = 0..15
      f32x4 d1 = __builtin_amdgcn_mfma_f32_16x16x32_bf16(bf1, af,
                   (f32x4){0.f, 0.f, 0.f, 0.f}, 0, 0, 0);   // o = 16..31
      float ws = w8[s];
#pragma unroll
      for (int r = 0; r < 4; ++r) {
        acc0[r] += ws * d0[r];
        acc1[r] += ws * d1[r];
      }
    }

    if (g * 16 + m < nE) {                         // lane's own edge valid?
      u32x4 pk;
      pk.x = (unsigned)(unsigned short)f2bs(acc0[0]) |
             ((unsigned)(unsigned short)f2bs(acc1[0]) << 16);
      pk.y = (unsigned)(unsigned short)f2bs(acc0[1]) |
             ((unsigned)(unsigned short)f2bs(acc1[1]) << 16);
      pk.z = (unsigned)(unsigned short)f2bs(acc0[2]) |
             ((unsigned)(unsigned short)f2bs(acc1[2]) << 16);
      pk.w = (unsigned)(unsigned short)f2bs(acc0[3]) |
             ((unsigned)(unsigned short)f2bs(acc1[3]) << 16);
      __builtin_nontemporal_store(pk, msg4 + (size_t)rp * 4 + kq);
    }

    if (!more) break;
    g = gn; ed = edn; af = afn; rp = rpn;
  }
}

// ---------------------------------------------------------------------------
// Per-node gather: 16 lanes/node. Messages for node n are CONTIGUOUS slots
// [rstart[n], rstart[n+1]) -> fully coalesced NT stream. Sum bf16 in fp32,
// divide by deg, add bias. Lane j holds channels o=j and o=j+16.
// ---------------------------------------------------------------------------
__global__ __launch_bounds__(256) void gather_out(const unsigned* __restrict__ msg,
                                                  const int* __restrict__ rstart,
                                                  const float* __restrict__ bias,
                                                  float* __restrict__ out) {
  int n = (blockIdx.x * 256 + threadIdx.x) >> 4;   // node
  int j = threadIdx.x & 15;
  if (n >= NN) return;
  int s = rstart[n], e = rstart[n + 1];
  int cnt = e - s;
  const unsigned* mp = msg + (size_t)s * 16 + j;
  float s0 = 0.f, s1 = 0.f;
  int i = 0;
  for (; i + 4 <= cnt; i += 4) {                   // unroll-4 for MLP
    unsigned uA = __builtin_nontemporal_load(mp + (size_t)(i + 0) * 16);
    unsigned uB = __builtin_nontemporal_load(mp + (size_t)(i + 1) * 16);
    unsigned uC = __builtin_nontemporal_load(mp + (size_t)(i + 2) * 16);
    unsigned uD = __builtin_nontemporal_load(mp + (size_t)(i + 3) * 16);
    s0 += __uint_as_float(uA << 16); s1 += __uint_as_float(uA & 0xFFFF0000u);
    s0 += __uint_as_float(uB << 16); s1 += __uint_as_float(uB & 0xFFFF0000u);
    s0 += __uint_as_float(uC << 16); s1 += __uint_as_float(uC & 0xFFFF0000u);
    s0 += __uint_as_float(uD << 16); s1 += __uint_as_float(uD & 0xFFFF0000u);
  }
  for (; i < cnt; ++i) {
    unsigned u = __builtin_nontemporal_load(mp + (size_t)i * 16);
    s0 += __uint_as_float(u << 16);
    s1 += __uint_as_float(u & 0xFFFF0000u);
  }
  float d = fmaxf((float)cnt, 1.0f);
  out[n * 32 + j]      = s0 / d + bias[j];
  out[n * 32 + 16 + j] = s1 / d + bias[16 + j];
}

// ---------------------------------------------------------------------------
// Fallback path (small workspace): direct per-edge compute + atomics.
// ---------------------------------------------------------------------------
static __device__ __forceinline__ void spline_basis(const float* __restrict__ pseudo,
                                                    int e, float w[8], int& base) {
  float v0 = pseudo[e * 3 + 0] * 3.0f;
  float v1 = pseudo[e * 3 + 1] * 3.0f;
  float v2 = pseudo[e * 3 + 2] * 3.0f;
  float b0 = fmaxf(fminf(floorf(v0), 2.0f), 0.0f);
  float b1 = fmaxf(fminf(floorf(v1), 2.0f), 0.0f);
  float b2 = fmaxf(fminf(floorf(v2), 2.0f), 0.0f);
  float f0 = v0 - b0, f1 = v1 - b1, f2 = v2 - b2;
  float g0 = 1.0f - f0, g1 = 1.0f - f1, g2 = 1.0f - f2;
  base = (int)b0 + 4 * (int)b1 + 16 * (int)b2;
  w[0] = g0 * g1 * g2; w[1] = f0 * g1 * g2;
  w[2] = g0 * f1 * g2; w[3] = f0 * f1 * g2;
  w[4] = g0 * g1 * f2; w[5] = f0 * g1 * f2;
  w[6] = g0 * f1 * f2; w[7] = f0 * f1 * f2;
}

__global__ __launch_bounds__(256) void edge_direct(const float* __restrict__ pseudo,
                                                   const int* __restrict__ ei,
                                                   const float* __restrict__ f,
                                                   const float* __restrict__ W,
                                                   float* __restrict__ acc,
                                                   float* __restrict__ deg) {
  const int tid = blockIdx.x * 256 + threadIdx.x;
  const int e = tid >> 5;
  const int o = tid & 31;
  if (e >= EE) return;
  const int row = ei[e];
  const int col = ei[EE + e];
  float w[8]; int base;
  spline_basis(pseudo, e, w, base);
  const float myf = f[col * 32 + o];
  float a = 0.0f;
  for (int i = 0; i < 32; ++i) {
    float fi = __shfl(myf, i, 32);
    float wsum = 0.0f;
#pragma unroll
    for (int s = 0; s < 8; ++s)
      wsum += w[s] * W[(size_t)(base + kOffs[s]) * 1024 + i * 32 + o];
    a += fi * wsum;
  }
  atomicAdd(acc + (size_t)row * 32 + o, a);
  if (o == 0) atomicAdd(deg + row, 1.0f);
}

__global__ __launch_bounds__(256) void finalize(const float* __restrict__ acc,
                                                const float* __restrict__ deg,
                                                const float* __restrict__ bias,
                                                float* __restrict__ out) {
  int tid = blockIdx.x * 256 + threadIdx.x;
  if (tid >= NN * 32) return;
  int n = tid >> 5, o = tid & 31;
  float d = fmaxf(deg[n], 1.0f);
  out[tid] = acc[tid] / d + bias[o];
}

extern "C" void kernel_launch(void* const* d_in, const int* in_sizes, int n_in,
                              void* d_out, int out_size, void* d_ws, size_t ws_size,
                              hipStream_t stream) {
  const float* f      = (const float*)d_in[0];
  const float* pseudo = (const float*)d_in[1];
  const float* W      = (const float*)d_in[2];
  const float* bias   = (const float*)d_in[3];
  const int*   ei     = (const int*)d_in[4];
  float* out = (float*)d_out;

  // Workspace layout (~154.3 MB total; no memset — all buffers fully written)
  constexpr size_t DEGI_OFF  = 0;                              // NN ints
  constexpr size_t BST_OFF   = 200064;                         // 28 ints
  constexpr size_t RST_OFF   = 200192;                         // NN+1 ints
  constexpr size_t BH_OFF    = 400256;                         // 27*NCHUNK ints
  constexpr size_t LRANK_OFF = 569088;                         // EE u16
  constexpr size_t GCNT_OFF  = LRANK_OFF + (size_t)EE * 2;     //   3,769,088
  constexpr size_t ED_OFF    = GCNT_OFF + (size_t)GG * NN * 4; //  29,369,088
  constexpr size_t RPOS_OFF  = ED_OFF + (size_t)EE * 8;        //  42,169,088
  constexpr size_t MSG_OFF   = RPOS_OFF + (size_t)EE * 4;      //  48,569,088
  constexpr size_t FBH_OFF   = MSG_OFF + (size_t)EE * 64;      // 150,969,088
  constexpr size_t WB_OFF    = FBH_OFF + (size_t)NN * 64;      // 154,169,088
  constexpr size_t TOTAL     = WB_OFF + 128 * 64 * 8 * 2;      // 154,300,160

  char* ws = (char*)d_ws;

  if (ws_size >= TOTAL) {
    int*            degi  = (int*)(ws + DEGI_OFF);
    int*            bst   = (int*)(ws + BST_OFF);
    int*            rst   = (int*)(ws + RST_OFF);
    int*            bh    = (int*)(ws + BH_OFF);
    unsigned short* lrank = (unsigned short*)(ws + LRANK_OFF);
    int*            gcnt  = (int*)(ws + GCNT_OFF);
    u32x2*          edata = (u32x2*)(ws + ED_OFF);
    int*            rpos  = (int*)(ws + RPOS_OFF);
    u32x4*          msg4  = (u32x4*)(ws + MSG_OFF);
    unsigned*       msg   = (unsigned*)(ws + MSG_OFF);
    short*          fbh   = (short*)(ws + FBH_OFF);
    short*          Wb    = (short*)(ws + WB_OFF);

    group_rank<<<GG, 256, 0, stream>>>(ei, lrank, gcnt);
    prep<<<PREP_BLOCKS, 256, 0, stream>>>(W, f, pseudo, Wb, fbh, bh);
    deg_total<<<(NN + 255) / 256, 256, 0, stream>>>(gcnt, degi);
    scan_combo<<<2, 1024, 0, stream>>>(bh, degi, bst, rst);
    group_base<<<(NN + 255) / 256, 256, 0, stream>>>(gcnt, rst);
    bucket_scatter<<<NCHUNK, 256, 0, stream>>>(pseudo, ei, lrank, gcnt, bh, edata, rpos);
    edge_mfma_nw<<<27 * BPB, 256, 0, stream>>>(edata, rpos, fbh, Wb, bst, msg4);
    gather_out<<<(NN * 16 + 255) / 256, 256, 0, stream>>>(msg, rst, bias, out);
  } else {
    constexpr size_t ACC_SZ = (size_t)NN * 32 * 4;
    float* acc = (float*)ws;
    float* deg = (float*)(ws + ACC_SZ);
    hipMemsetAsync(acc, 0, ACC_SZ + (size_t)NN * 4, stream);
    edge_direct<<<(EE * 32) / 256, 256, 0, stream>>>(pseudo, ei, f, W, acc, deg);
    finalize<<<(NN * 32) / 256, 256, 0, stream>>>(acc, deg, bias, out);
  }
}

// Round 12
// 277.848 us; speedup vs baseline: 1.2808x; 1.2808x over previous
//
#include <hip/hip_runtime.h>
#include <hip/hip_bf16.h>

// Problem constants: N=50000, E=1600000, D=3, IN=32, OUT=32, KS=4, K=64, S=8
// Round-12: revert R11's NT hints + LDS-W staging (both regressed: NT broke
// inter-kernel L2/L3 producer->consumer reuse; LDS-W was hoisted back to regs
// by the compiler, VGPR stayed 116). Keep R11's 8B-packed edata (numerics
// proven identical). Add depth-2 prefetch pipeline in edge_mfma_nw to break
// the serialized edata->fbh dependent-latency chain R8's counters showed.
//   group_rank: 128 edge-groups; full 50K-row LDS histogram (2 rows/u32,
//       100 KB); LDS atomic return = lrank[e]; counts -> gcnt[g][row].
//   prep: pack W/f to bf16 + per-chunk 27-bin bucket histogram.
//   deg_total: degi[row] = sum_g gcnt[g][row].
//   scan_combo: blk0 scans bh[27][NCHUNK]; blk1 scans degi -> rstart.
//   group_base: gcnt[g][row] = rstart[row] + prefix_g (in place).
//   bucket_scatter: counting sort; edata PACKED 8 B (frac unorm16 x3 + col
//       u16); rpos = gcnt[e/GSZ][row] + lrank[e]. LDS atomics only.
//   edge_mfma_nw: per-bucket MFMA, swapped operands, W frags in VGPRs,
//       DEPTH-2 edata/rpos prefetch + depth-1 fbh prefetch; one dwordx4
//       msg store at the edge's row-sorted slot.
//   gather_out: per node, contiguous [rstart[n],rstart[n+1]) coalesced sum.
#define NN 50000
#define EE 1600000
#define BPB 96               // blocks per bucket in edge_mfma_nw
#define CH 1024              // edges per chunk (bucket hist/scatter)
#define NCHUNK ((EE + CH - 1) / CH)   // 1563
#define GG 128               // rank groups
#define GSZ (EE / GG)        // 12500 edges per group (exact)

typedef __attribute__((ext_vector_type(8))) short    s16x8;   // 8 bf16 (4 VGPRs)
typedef __attribute__((ext_vector_type(4))) float    f32x4;   // MFMA C/D frag
typedef __attribute__((ext_vector_type(2))) unsigned u32x2;   // 8 B packed edge
typedef __attribute__((ext_vector_type(4))) unsigned u32x4;   // 16 B msg store

static __device__ __forceinline__ short f2bs(float x) {
  __hip_bfloat16 h = __float2bfloat16(x);
  short s; __builtin_memcpy(&s, &h, 2); return s;
}

__constant__ int kOffs[8] = {0, 1, 4, 5, 16, 17, 20, 21};

// ---------------------------------------------------------------------------
// group_rank: block g owns edges [g*GSZ,(g+1)*GSZ). Full-row histogram in LDS
// (2 rows/u32; halves never carry since per-half count <= 12500 < 65536).
// LDS atomic RETURN = within-(group,row) rank -> lrank[e].
// ---------------------------------------------------------------------------
__global__ __launch_bounds__(256) void group_rank(const int* __restrict__ ei,
                                                  unsigned short* __restrict__ lrank,
                                                  int* __restrict__ gcnt) {
  __shared__ unsigned lh32[NN / 2];                // 25000 words = 100 KB
  for (int j = threadIdx.x; j < NN / 2; j += 256) lh32[j] = 0;
  __syncthreads();
  const int g  = blockIdx.x;
  const int e0 = g * GSZ;
  for (int i = threadIdx.x; i < GSZ; i += 256) {
    int e = e0 + i;
    int row = ei[e];
    unsigned add = (row & 1) ? 0x10000u : 1u;
    unsigned ret = atomicAdd(&lh32[row >> 1], add);
    unsigned r = (row & 1) ? (ret >> 16) : (ret & 0xFFFFu);
    lrank[e] = (unsigned short)r;
  }
  __syncthreads();
  for (int j = threadIdx.x; j < NN / 2; j += 256) {
    unsigned u = lh32[j];
    gcnt[(size_t)g * NN + 2 * j]     = (int)(u & 0xFFFFu);
    gcnt[(size_t)g * NN + 2 * j + 1] = (int)(u >> 16);
  }
}

// ---------------------------------------------------------------------------
// prep (fused): blocks [0,32) conv_w ; [32,160) pack_f ; [160,160+NCHUNK)
// per-chunk 27-bin bucket histogram (LDS-only atomics).
// conv_w frag layout: (tile t=kmat*2+oh, lane l, j) =
//   W[kmat][(l>>4)*8+j][oh*16+(l&15)] — read as A-frag it is W^T.
// ---------------------------------------------------------------------------
#define PREP_BLOCKS (160 + NCHUNK)
__global__ __launch_bounds__(256) void prep(const float* __restrict__ W,
                                            const float* __restrict__ f,
                                            const float* __restrict__ pseudo,
                                            short* __restrict__ Wb,
                                            short* __restrict__ fbh,
                                            int* __restrict__ bh) {
  const int b = blockIdx.x;
  if (b < 32) {
    int tid = b * 256 + threadIdx.x;               // 8192 threads, one frag each
    int t = tid >> 6, l = tid & 63;
    int c = t * 16 + (l & 15);
    int k0 = (l >> 4) * 8;
    s16x8 frag;
#pragma unroll
    for (int j = 0; j < 8; ++j)
      frag[j] = f2bs(W[(c >> 5) * 1024 + (k0 + j) * 32 + (c & 31)]);
    ((s16x8*)Wb)[tid] = frag;
  } else if (b < 160) {
    for (int tid = (b - 32) * 256 + threadIdx.x; tid < NN * 32 / 8; tid += 128 * 256) {
      const f32x4* fp = (const f32x4*)f + (size_t)tid * 2;
      f32x4 a = fp[0], c = fp[1];
      s16x8 o;
#pragma unroll
      for (int j = 0; j < 4; ++j) { o[j] = f2bs(a[j]); o[4 + j] = f2bs(c[j]); }
      ((s16x8*)fbh)[tid] = o;
    }
  } else {
    __shared__ int lh[27];
    if (threadIdx.x < 27) lh[threadIdx.x] = 0;
    __syncthreads();
    const int c  = b - 160;                        // chunk id
    const int e0 = c * CH;
#pragma unroll
    for (int i = 0; i < CH / 256; ++i) {
      int e = e0 + i * 256 + threadIdx.x;
      if (e < EE) {
        float v0 = pseudo[e * 3 + 0] * 3.0f;
        float v1 = pseudo[e * 3 + 1] * 3.0f;
        float v2 = pseudo[e * 3 + 2] * 3.0f;
        int b0 = (int)fminf(fmaxf(floorf(v0), 0.0f), 2.0f);
        int b1 = (int)fminf(fmaxf(floorf(v1), 0.0f), 2.0f);
        int b2 = (int)fminf(fmaxf(floorf(v2), 0.0f), 2.0f);
        atomicAdd(&lh[b0 + 3 * b1 + 9 * b2], 1);
      }
    }
    __syncthreads();
    if (threadIdx.x < 27) bh[threadIdx.x * NCHUNK + c] = lh[threadIdx.x];
  }
}

// ---------------------------------------------------------------------------
// deg_total: degi[row] = sum over groups of gcnt[g][row] (coalesced per g).
// ---------------------------------------------------------------------------
__global__ __launch_bounds__(256) void deg_total(const int* __restrict__ gcnt,
                                                 int* __restrict__ degi) {
  int row = blockIdx.x * 256 + threadIdx.x;
  if (row >= NN) return;
  int s = 0;
#pragma unroll 8
  for (int g = 0; g < GG; ++g) s += gcnt[(size_t)g * NN + row];
  degi[row] = s;
}

// ---------------------------------------------------------------------------
// scan_combo (grid=2, 1024 threads):
//   block 0: in-place exclusive scan of bh[27*NCHUNK] (bin-major flat), then
//            bstart[q] = bh[q*NCHUNK] (bstart[27] = EE).
//   block 1: exclusive scan of degi[50000] -> rstart[0..NN].
// ---------------------------------------------------------------------------
__global__ __launch_bounds__(1024) void scan_combo(int* __restrict__ bh,
                                                   const int* __restrict__ degi,
                                                   int* __restrict__ bstart,
                                                   int* __restrict__ rstart) {
  __shared__ int carry;
  __shared__ int tot;
  __shared__ int wsum[16];
  const int lane = threadIdx.x & 63;
  const int wid  = threadIdx.x >> 6;
  if (threadIdx.x == 0) carry = 0;
  __syncthreads();
  if (blockIdx.x == 0) {
    const int L = 27 * NCHUNK;
    for (int c0 = 0; c0 < L; c0 += 1024) {
      int i = c0 + threadIdx.x;
      int v = (i < L) ? bh[i] : 0;
      int x = v;
#pragma unroll
      for (int d = 1; d < 64; d <<= 1) {
        int y = __shfl_up(x, d, 64);
        if (lane >= d) x += y;
      }
      if (lane == 63) wsum[wid] = x;
      __syncthreads();
      if (threadIdx.x == 0) {
        int run = 0;
#pragma unroll
        for (int w = 0; w < 16; ++w) { int t = wsum[w]; wsum[w] = run; run += t; }
        tot = run;
      }
      __syncthreads();
      int excl = carry + wsum[wid] + (x - v);
      if (i < L) bh[i] = excl;
      __syncthreads();
      if (threadIdx.x == 0) carry += tot;
      __syncthreads();
    }
    if (threadIdx.x < 27) bstart[threadIdx.x] = bh[threadIdx.x * NCHUNK];
    if (threadIdx.x == 27) bstart[27] = EE;
  } else {
    for (int c0 = 0; c0 < NN; c0 += 1024) {
      int i = c0 + threadIdx.x;
      int v = (i < NN) ? degi[i] : 0;
      int x = v;
#pragma unroll
      for (int d = 1; d < 64; d <<= 1) {
        int y = __shfl_up(x, d, 64);
        if (lane >= d) x += y;
      }
      if (lane == 63) wsum[wid] = x;
      __syncthreads();
      if (threadIdx.x == 0) {
        int run = 0;
#pragma unroll
        for (int w = 0; w < 16; ++w) { int t = wsum[w]; wsum[w] = run; run += t; }
        tot = run;
      }
      __syncthreads();
      int excl = carry + wsum[wid] + (x - v);
      if (i < NN) rstart[i] = excl;
      __syncthreads();
      if (threadIdx.x == 0) carry += tot;
      __syncthreads();
    }
    if (threadIdx.x == 0) rstart[NN] = carry;      // == EE
  }
}

// ---------------------------------------------------------------------------
// group_base: in-place gcnt[g][row] = rstart[row] + prefix over g'<g.
// Loads batched 8-wide so the 128-step chain isn't latency-serialized.
// ---------------------------------------------------------------------------
__global__ __launch_bounds__(256) void group_base(int* __restrict__ gcnt,
                                                  const int* __restrict__ rstart) {
  int row = blockIdx.x * 256 + threadIdx.x;
  if (row >= NN) return;
  int run = rstart[row];
  for (int g0 = 0; g0 < GG; g0 += 8) {
    int t[8];
#pragma unroll
    for (int j = 0; j < 8; ++j) t[j] = gcnt[(size_t)(g0 + j) * NN + row];
#pragma unroll
    for (int j = 0; j < 8; ++j) {
      int v = t[j];
      gcnt[(size_t)(g0 + j) * NN + row] = run;
      run += v;
    }
  }
}

// ---------------------------------------------------------------------------
// Counting-sort scatter, ZERO global atomics. 1 block = 1 chunk (same edge
// partitioning as prep's hist). Rank within (chunk,bin) via LDS atomics;
// base = pre-scanned bh[q*NCHUNK+c].
// edata PACKED 8 B: x = f0q | f1q<<16, y = f2q | col<<16  (frac unorm16,
// quantization err ~2e-5 in spline weights — verified R11, absmax identical).
// rpos_arr[pos] = gcnt[e/GSZ][row] + lrank[e]   (row-sorted message slot).
// ---------------------------------------------------------------------------
static __device__ __forceinline__ unsigned q16(float fr) {
  return min((unsigned)(fr * 65536.0f), 65535u);
}
__global__ __launch_bounds__(256) void bucket_scatter(const float* __restrict__ pseudo,
                                                      const int* __restrict__ ei,
                                                      const unsigned short* __restrict__ lrank,
                                                      const int* __restrict__ gcnt,
                                                      const int* __restrict__ bh,
                                                      u32x2* __restrict__ edata,
                                                      int* __restrict__ rpos_arr) {
  __shared__ int lh[27];
  __shared__ int bb[27];
  if (threadIdx.x < 27) {
    lh[threadIdx.x] = 0;
    bb[threadIdx.x] = bh[threadIdx.x * NCHUNK + blockIdx.x];
  }
  __syncthreads();
  const int e0 = blockIdx.x * CH;
#pragma unroll
  for (int i = 0; i < CH / 256; ++i) {
    int e = e0 + i * 256 + threadIdx.x;
    if (e < EE) {
      float v0 = pseudo[e * 3 + 0] * 3.0f;
      float v1 = pseudo[e * 3 + 1] * 3.0f;
      float v2 = pseudo[e * 3 + 2] * 3.0f;
      float fb0 = fmaxf(fminf(floorf(v0), 2.0f), 0.0f);
      float fb1 = fmaxf(fminf(floorf(v1), 2.0f), 0.0f);
      float fb2 = fmaxf(fminf(floorf(v2), 2.0f), 0.0f);
      int q = (int)fb0 + 3 * (int)fb1 + 9 * (int)fb2;
      int rk = atomicAdd(&lh[q], 1);
      int pos = bb[q] + rk;
      int row = ei[e];
      int col = ei[EE + e];
      int ge  = e / GSZ;
      u32x2 pk;
      pk.x = q16(v0 - fb0) | (q16(v1 - fb1) << 16);
      pk.y = q16(v2 - fb2) | ((unsigned)col << 16);
      edata[pos] = pk;
      rpos_arr[pos] = gcnt[(size_t)ge * NN + row] + (int)lrank[e];
    }
  }
}

// ---------------------------------------------------------------------------
// Bucketed MFMA, atomic-free, SWAPPED OPERANDS, DEPTH-2 PIPELINE.
// Per group of 16 edges: D = mfma(A=W^T tile (VGPR frags), B=f^T (fbh), 0)
//   -> D[row=(l>>4)*4+r = o-channel][col=l&15 = edge]  (m89 layout).
// Lane l owns edge m=l&15; weights + rpos lane-local (no cross-lane ops).
// Pipeline: edata/rpos fetched TWO groups ahead; fbh gather ONE group ahead
// using an edata value that landed a full iteration earlier — breaks the
// serialized edata->fbh dependent chain (R8's 63% stall).
// Store: ONE dwordx4 per lane: msg4[rp*4+kq] = {pk(o,o+16)}_{r=0..3}.
// ---------------------------------------------------------------------------
__global__ __launch_bounds__(256) void edge_mfma_nw(const u32x2* __restrict__ edata,
                                                    const int* __restrict__ rpos_arr,
                                                    const short* __restrict__ fbh,
                                                    const short* __restrict__ Wb,
                                                    const int* __restrict__ bstart,
                                                    u32x4* __restrict__ msg4) {
  const int q   = blockIdx.x / BPB;
  const int sub = blockIdx.x % BPB;
  const int l   = threadIdx.x & 63;
  const int wid = threadIdx.x >> 6;

  const int start = bstart[q];
  const int end   = bstart[q + 1];
  const int nE    = end - start;
  if (nE <= 0) return;
  const int ngroups = (nE + 15) >> 4;

  const int b0 = q % 3, b1 = (q / 3) % 3, b2 = q / 9;
  const int base = b0 + 4 * b1 + 16 * b2;
  const int ko[8] = {0, 1, 4, 5, 16, 17, 20, 21};

  s16x8 bf[8][2];                                  // bucket's W frags, 64 VGPRs
#pragma unroll
  for (int s = 0; s < 8; ++s) {
    int kmat = base + ko[s];
#pragma unroll
    for (int oh = 0; oh < 2; ++oh)
      bf[s][oh] = ((const s16x8*)Wb)[(kmat * 2 + oh) * 64 + l];
  }

  const int m   = l & 15;         // edge-in-group OWNED by this lane
  const int kq  = l >> 4;         // B k-chunk / D o-quarter
  const int stride = BPB * 4;
  const float inv16 = 1.0f / 65536.0f;

  int gA = sub * 4 + wid;
  if (gA >= ngroups) return;
  int gB = gA + stride;

  // clamped indices (invalid -> start; garbage compute, store guarded)
  int iA = start + gA * 16 + m;  int ciA = iA < end ? iA : start;
  int iB = start + gB * 16 + m;  int ciB = (gB < ngroups && iB < end) ? iB : start;

  u32x2 edA = edata[ciA];  int rpA = rpos_arr[ciA];
  u32x2 edB = edata[ciB];  int rpB = rpos_arr[ciB];
  s16x8 afA = ((const s16x8*)fbh)[(size_t)(edA.y >> 16) * 4 + kq];

  while (true) {
    const bool moreB = gB < ngroups;
    const int gC = gB + stride;
    int iC = start + gC * 16 + m;
    int ciC = (gC < ngroups && iC < end) ? iC : start;
    u32x2 edC = edata[ciC];                        // depth-2 prefetch
    int   rpC = rpos_arr[ciC];
    // depth-1 fbh prefetch — edB landed a full iteration ago
    s16x8 afB = ((const s16x8*)fbh)[(size_t)(edB.y >> 16) * 4 + kq];

    // spline weights of this lane's OWN edge (unorm16 fracs)
    float f0 = (float)(edA.x & 0xFFFFu) * inv16;
    float f1 = (float)(edA.x >> 16)     * inv16;
    float f2 = (float)(edA.y & 0xFFFFu) * inv16;
    float g0 = 1.0f - f0, g1c = 1.0f - f1, g2c = 1.0f - f2;
    float w8[8];
    w8[0] = g0 * g1c * g2c; w8[1] = f0 * g1c * g2c;
    w8[2] = g0 * f1 * g2c;  w8[3] = f0 * f1 * g2c;
    w8[4] = g0 * g1c * f2;  w8[5] = f0 * g1c * f2;
    w8[6] = g0 * f1 * f2;   w8[7] = f0 * f1 * f2;

    f32x4 acc0 = {0.f, 0.f, 0.f, 0.f}, acc1 = {0.f, 0.f, 0.f, 0.f};
#pragma unroll
    for (int s = 0; s < 8; ++s) {
      f32x4 d0 = __builtin_amdgcn_mfma_f32_16x16x32_bf16(bf[s][0], afA,
                   (f32x4){0.f, 0.f, 0.f, 0.f}, 0, 0, 0);   // o = 0..15
      f32x4 d1 = __builtin_amdgcn_mfma_f32_16x16x32_bf16(bf[s][1], afA,
                   (f32x4){0.f, 0.f, 0.f, 0.f}, 0, 0, 0);   // o = 16..31
      float ws = w8[s];
#pragma unroll
      for (int r = 0; r < 4; ++r) {
        acc0[r] += ws * d0[r];
        acc1[r] += ws * d1[r];
      }
    }

    if (gA * 16 + m < nE) {                        // lane's own edge valid?
      u32x4 pk;
      pk.x = (unsigned)(unsigned short)f2bs(acc0[0]) |
             ((unsigned)(unsigned short)f2bs(acc1[0]) << 16);
      pk.y = (unsigned)(unsigned short)f2bs(acc0[1]) |
             ((unsigned)(unsigned short)f2bs(acc1[1]) << 16);
      pk.z = (unsigned)(unsigned short)f2bs(acc0[2]) |
             ((unsigned)(unsigned short)f2bs(acc1[2]) << 16);
      pk.w = (unsigned)(unsigned short)f2bs(acc0[3]) |
             ((unsigned)(unsigned short)f2bs(acc1[3]) << 16);
      msg4[(size_t)rpA * 4 + kq] = pk;             // one 16 B store per lane
    }

    if (!moreB) break;
    gA = gB; edA = edB; rpA = rpB; afA = afB;
    gB = gC; edB = edC; rpB = rpC;
  }
}

// ---------------------------------------------------------------------------
// Per-node gather: 16 lanes/node. Messages for node n are CONTIGUOUS slots
// [rstart[n], rstart[n+1]) -> fully coalesced stream. Sum bf16 in fp32,
// divide by deg, add bias. Lane j holds channels o=j and o=j+16.
// ---------------------------------------------------------------------------
__global__ __launch_bounds__(256) void gather_out(const unsigned* __restrict__ msg,
                                                  const int* __restrict__ rstart,
                                                  const float* __restrict__ bias,
                                                  float* __restrict__ out) {
  int n = (blockIdx.x * 256 + threadIdx.x) >> 4;   // node
  int j = threadIdx.x & 15;
  if (n >= NN) return;
  int s = rstart[n], e = rstart[n + 1];
  int cnt = e - s;
  const unsigned* mp = msg + (size_t)s * 16 + j;
  float s0 = 0.f, s1 = 0.f;
  int i = 0;
  for (; i + 4 <= cnt; i += 4) {                   // unroll-4 for MLP
    unsigned uA = mp[(size_t)(i + 0) * 16];
    unsigned uB = mp[(size_t)(i + 1) * 16];
    unsigned uC = mp[(size_t)(i + 2) * 16];
    unsigned uD = mp[(size_t)(i + 3) * 16];
    s0 += __uint_as_float(uA << 16); s1 += __uint_as_float(uA & 0xFFFF0000u);
    s0 += __uint_as_float(uB << 16); s1 += __uint_as_float(uB & 0xFFFF0000u);
    s0 += __uint_as_float(uC << 16); s1 += __uint_as_float(uC & 0xFFFF0000u);
    s0 += __uint_as_float(uD << 16); s1 += __uint_as_float(uD & 0xFFFF0000u);
  }
  for (; i < cnt; ++i) {
    unsigned u = mp[(size_t)i * 16];
    s0 += __uint_as_float(u << 16);
    s1 += __uint_as_float(u & 0xFFFF0000u);
  }
  float d = fmaxf((float)cnt, 1.0f);
  out[n * 32 + j]      = s0 / d + bias[j];
  out[n * 32 + 16 + j] = s1 / d + bias[16 + j];
}

// ---------------------------------------------------------------------------
// Fallback path (small workspace): direct per-edge compute + atomics.
// ---------------------------------------------------------------------------
static __device__ __forceinline__ void spline_basis(const float* __restrict__ pseudo,
                                                    int e, float w[8], int& base) {
  float v0 = pseudo[e * 3 + 0] * 3.0f;
  float v1 = pseudo[e * 3 + 1] * 3.0f;
  float v2 = pseudo[e * 3 + 2] * 3.0f;
  float b0 = fmaxf(fminf(floorf(v0), 2.0f), 0.0f);
  float b1 = fmaxf(fminf(floorf(v1), 2.0f), 0.0f);
  float b2 = fmaxf(fminf(floorf(v2), 2.0f), 0.0f);
  float f0 = v0 - b0, f1 = v1 - b1, f2 = v2 - b2;
  float g0 = 1.0f - f0, g1 = 1.0f - f1, g2 = 1.0f - f2;
  base = (int)b0 + 4 * (int)b1 + 16 * (int)b2;
  w[0] = g0 * g1 * g2; w[1] = f0 * g1 * g2;
  w[2] = g0 * f1 * g2; w[3] = f0 * f1 * g2;
  w[4] = g0 * g1 * f2; w[5] = f0 * g1 * f2;
  w[6] = g0 * f1 * f2; w[7] = f0 * f1 * f2;
}

__global__ __launch_bounds__(256) void edge_direct(const float* __restrict__ pseudo,
                                                   const int* __restrict__ ei,
                                                   const float* __restrict__ f,
                                                   const float* __restrict__ W,
                                                   float* __restrict__ acc,
                                                   float* __restrict__ deg) {
  const int tid = blockIdx.x * 256 + threadIdx.x;
  const int e = tid >> 5;
  const int o = tid & 31;
  if (e >= EE) return;
  const int row = ei[e];
  const int col = ei[EE + e];
  float w[8]; int base;
  spline_basis(pseudo, e, w, base);
  const float myf = f[col * 32 + o];
  float a = 0.0f;
  for (int i = 0; i < 32; ++i) {
    float fi = __shfl(myf, i, 32);
    float wsum = 0.0f;
#pragma unroll
    for (int s = 0; s < 8; ++s)
      wsum += w[s] * W[(size_t)(base + kOffs[s]) * 1024 + i * 32 + o];
    a += fi * wsum;
  }
  atomicAdd(acc + (size_t)row * 32 + o, a);
  if (o == 0) atomicAdd(deg + row, 1.0f);
}

__global__ __launch_bounds__(256) void finalize(const float* __restrict__ acc,
                                                const float* __restrict__ deg,
                                                const float* __restrict__ bias,
                                                float* __restrict__ out) {
  int tid = blockIdx.x * 256 + threadIdx.x;
  if (tid >= NN * 32) return;
  int n = tid >> 5, o = tid & 31;
  float d = fmaxf(deg[n], 1.0f);
  out[tid] = acc[tid] / d + bias[o];
}

extern "C" void kernel_launch(void* const* d_in, const int* in_sizes, int n_in,
                              void* d_out, int out_size, void* d_ws, size_t ws_size,
                              hipStream_t stream) {
  const float* f      = (const float*)d_in[0];
  const float* pseudo = (const float*)d_in[1];
  const float* W      = (const float*)d_in[2];
  const float* bias   = (const float*)d_in[3];
  const int*   ei     = (const int*)d_in[4];
  float* out = (float*)d_out;

  // Workspace layout (~154.3 MB total; no memset — all buffers fully written)
  constexpr size_t DEGI_OFF  = 0;                              // NN ints
  constexpr size_t BST_OFF   = 200064;                         // 28 ints
  constexpr size_t RST_OFF   = 200192;                         // NN+1 ints
  constexpr size_t BH_OFF    = 400256;                         // 27*NCHUNK ints
  constexpr size_t LRANK_OFF = 569088;                         // EE u16
  constexpr size_t GCNT_OFF  = LRANK_OFF + (size_t)EE * 2;     //   3,769,088
  constexpr size_t ED_OFF    = GCNT_OFF + (size_t)GG * NN * 4; //  29,369,088
  constexpr size_t RPOS_OFF  = ED_OFF + (size_t)EE * 8;        //  42,169,088
  constexpr size_t MSG_OFF   = RPOS_OFF + (size_t)EE * 4;      //  48,569,088
  constexpr size_t FBH_OFF   = MSG_OFF + (size_t)EE * 64;      // 150,969,088
  constexpr size_t WB_OFF    = FBH_OFF + (size_t)NN * 64;      // 154,169,088
  constexpr size_t TOTAL     = WB_OFF + 128 * 64 * 8 * 2;      // 154,300,160

  char* ws = (char*)d_ws;

  if (ws_size >= TOTAL) {
    int*            degi  = (int*)(ws + DEGI_OFF);
    int*            bst   = (int*)(ws + BST_OFF);
    int*            rst   = (int*)(ws + RST_OFF);
    int*            bh    = (int*)(ws + BH_OFF);
    unsigned short* lrank = (unsigned short*)(ws + LRANK_OFF);
    int*            gcnt  = (int*)(ws + GCNT_OFF);
    u32x2*          edata = (u32x2*)(ws + ED_OFF);
    int*            rpos  = (int*)(ws + RPOS_OFF);
    u32x4*          msg4  = (u32x4*)(ws + MSG_OFF);
    unsigned*       msg   = (unsigned*)(ws + MSG_OFF);
    short*          fbh   = (short*)(ws + FBH_OFF);
    short*          Wb    = (short*)(ws + WB_OFF);

    group_rank<<<GG, 256, 0, stream>>>(ei, lrank, gcnt);
    prep<<<PREP_BLOCKS, 256, 0, stream>>>(W, f, pseudo, Wb, fbh, bh);
    deg_total<<<(NN + 255) / 256, 256, 0, stream>>>(gcnt, degi);
    scan_combo<<<2, 1024, 0, stream>>>(bh, degi, bst, rst);
    group_base<<<(NN + 255) / 256, 256, 0, stream>>>(gcnt, rst);
    bucket_scatter<<<NCHUNK, 256, 0, stream>>>(pseudo, ei, lrank, gcnt, bh, edata, rpos);
    edge_mfma_nw<<<27 * BPB, 256, 0, stream>>>(edata, rpos, fbh, Wb, bst, msg4);
    gather_out<<<(NN * 16 + 255) / 256, 256, 0, stream>>>(msg, rst, bias, out);
  } else {
    constexpr size_t ACC_SZ = (size_t)NN * 32 * 4;
    float* acc = (float*)ws;
    float* deg = (float*)(ws + ACC_SZ);
    hipMemsetAsync(acc, 0, ACC_SZ + (size_t)NN * 4, stream);
    edge_direct<<<(EE * 32) / 256, 256, 0, stream>>>(pseudo, ei, f, W, acc, deg);
    finalize<<<(NN * 32) / 256, 256, 0, stream>>>(acc, deg, bias, out);
  }
}

// Round 13
// 252.361 us; speedup vs baseline: 1.4101x; 1.1010x over previous
//
#include <hip/hip_runtime.h>
#include <hip/hip_bf16.h>

// Problem constants: N=50000, E=1600000, D=3, IN=32, OUT=32, KS=4, K=64, S=8
// R13: R12 (277.8 us, best) with the serial 2-block scan_combo + deg_total
// replaced by a 3-phase PARALLEL scan (sum_p1 / scan_tiny / scan_p3).
// Everything else byte-identical to R12.
//   group_rank: 128 edge-groups; full 50K-row LDS histogram (2 rows/u32,
//       100 KB); LDS atomic return = lrank[e]; counts -> gcnt[g][row].
//   prep: pack W/f to bf16 + per-chunk 27-bin bucket histogram.
//   sum_p1: blocks 0-195: degi[row] = sum_g gcnt[g][row] + block partial
//       rpart[b]; blocks 196-222: btot[q] = sum_c bh[q][c].
//   scan_tiny: 1 block: exclusive scans rpart->rpartx, btot->bstart.
//   scan_p3: blocks 0-195: rstart[row] = rpartx[b] + block-excl(degi);
//       blocks 196-222: bh[q][c] = bstart[q] + within-bucket prefix.
//   group_base: gcnt[g][row] = rstart[row] + prefix_g (in place).
//   bucket_scatter: counting sort; edata PACKED 8 B; rpos = gcnt + lrank.
//   edge_mfma_nw: per-bucket MFMA, swapped operands, depth-2 pipeline.
//   gather_out: per node, contiguous coalesced sum.
#define NN 50000
#define EE 1600000
#define BPB 96               // blocks per bucket in edge_mfma_nw
#define CH 1024              // edges per chunk (bucket hist/scatter)
#define NCHUNK ((EE + CH - 1) / CH)   // 1563
#define GG 128               // rank groups
#define GSZ (EE / GG)        // 12500 edges per group (exact)
#define NRB 196              // row blocks (ceil(NN/256))

typedef __attribute__((ext_vector_type(8))) short    s16x8;   // 8 bf16 (4 VGPRs)
typedef __attribute__((ext_vector_type(4))) float    f32x4;   // MFMA C/D frag
typedef __attribute__((ext_vector_type(2))) unsigned u32x2;   // 8 B packed edge
typedef __attribute__((ext_vector_type(4))) unsigned u32x4;   // 16 B msg store

static __device__ __forceinline__ short f2bs(float x) {
  __hip_bfloat16 h = __float2bfloat16(x);
  short s; __builtin_memcpy(&s, &h, 2); return s;
}

__constant__ int kOffs[8] = {0, 1, 4, 5, 16, 17, 20, 21};

// ---------------------------------------------------------------------------
// group_rank: block g owns edges [g*GSZ,(g+1)*GSZ). Full-row histogram in LDS
// (2 rows/u32; halves never carry since per-half count <= 12500 < 65536).
// LDS atomic RETURN = within-(group,row) rank -> lrank[e].
// ---------------------------------------------------------------------------
__global__ __launch_bounds__(256) void group_rank(const int* __restrict__ ei,
                                                  unsigned short* __restrict__ lrank,
                                                  int* __restrict__ gcnt) {
  __shared__ unsigned lh32[NN / 2];                // 25000 words = 100 KB
  for (int j = threadIdx.x; j < NN / 2; j += 256) lh32[j] = 0;
  __syncthreads();
  const int g  = blockIdx.x;
  const int e0 = g * GSZ;
  for (int i = threadIdx.x; i < GSZ; i += 256) {
    int e = e0 + i;
    int row = ei[e];
    unsigned add = (row & 1) ? 0x10000u : 1u;
    unsigned ret = atomicAdd(&lh32[row >> 1], add);
    unsigned r = (row & 1) ? (ret >> 16) : (ret & 0xFFFFu);
    lrank[e] = (unsigned short)r;
  }
  __syncthreads();
  for (int j = threadIdx.x; j < NN / 2; j += 256) {
    unsigned u = lh32[j];
    gcnt[(size_t)g * NN + 2 * j]     = (int)(u & 0xFFFFu);
    gcnt[(size_t)g * NN + 2 * j + 1] = (int)(u >> 16);
  }
}

// ---------------------------------------------------------------------------
// prep (fused): blocks [0,32) conv_w ; [32,160) pack_f ; [160,160+NCHUNK)
// per-chunk 27-bin bucket histogram (LDS-only atomics).
// conv_w frag layout: (tile t=kmat*2+oh, lane l, j) =
//   W[kmat][(l>>4)*8+j][oh*16+(l&15)] — read as A-frag it is W^T.
// ---------------------------------------------------------------------------
#define PREP_BLOCKS (160 + NCHUNK)
__global__ __launch_bounds__(256) void prep(const float* __restrict__ W,
                                            const float* __restrict__ f,
                                            const float* __restrict__ pseudo,
                                            short* __restrict__ Wb,
                                            short* __restrict__ fbh,
                                            int* __restrict__ bh) {
  const int b = blockIdx.x;
  if (b < 32) {
    int tid = b * 256 + threadIdx.x;               // 8192 threads, one frag each
    int t = tid >> 6, l = tid & 63;
    int c = t * 16 + (l & 15);
    int k0 = (l >> 4) * 8;
    s16x8 frag;
#pragma unroll
    for (int j = 0; j < 8; ++j)
      frag[j] = f2bs(W[(c >> 5) * 1024 + (k0 + j) * 32 + (c & 31)]);
    ((s16x8*)Wb)[tid] = frag;
  } else if (b < 160) {
    for (int tid = (b - 32) * 256 + threadIdx.x; tid < NN * 32 / 8; tid += 128 * 256) {
      const f32x4* fp = (const f32x4*)f + (size_t)tid * 2;
      f32x4 a = fp[0], c = fp[1];
      s16x8 o;
#pragma unroll
      for (int j = 0; j < 4; ++j) { o[j] = f2bs(a[j]); o[4 + j] = f2bs(c[j]); }
      ((s16x8*)fbh)[tid] = o;
    }
  } else {
    __shared__ int lh[27];
    if (threadIdx.x < 27) lh[threadIdx.x] = 0;
    __syncthreads();
    const int c  = b - 160;                        // chunk id
    const int e0 = c * CH;
#pragma unroll
    for (int i = 0; i < CH / 256; ++i) {
      int e = e0 + i * 256 + threadIdx.x;
      if (e < EE) {
        float v0 = pseudo[e * 3 + 0] * 3.0f;
        float v1 = pseudo[e * 3 + 1] * 3.0f;
        float v2 = pseudo[e * 3 + 2] * 3.0f;
        int b0 = (int)fminf(fmaxf(floorf(v0), 0.0f), 2.0f);
        int b1 = (int)fminf(fmaxf(floorf(v1), 0.0f), 2.0f);
        int b2 = (int)fminf(fmaxf(floorf(v2), 0.0f), 2.0f);
        atomicAdd(&lh[b0 + 3 * b1 + 9 * b2], 1);
      }
    }
    __syncthreads();
    if (threadIdx.x < 27) bh[threadIdx.x * NCHUNK + c] = lh[threadIdx.x];
  }
}

// ---------------------------------------------------------------------------
// sum_p1 (223 blocks): blocks [0,196): degi[row] = sum_g gcnt[g][row]
// (coalesced per g) + block partial sum -> rpart[b].
// Blocks [196,223): btot[q] = sum_c bh[q][c].
// ---------------------------------------------------------------------------
__global__ __launch_bounds__(256) void sum_p1(const int* __restrict__ gcnt,
                                              const int* __restrict__ bh,
                                              int* __restrict__ degi,
                                              int* __restrict__ rpart,
                                              int* __restrict__ btot) {
  const int b = blockIdx.x;
  const int lane = threadIdx.x & 63;
  const int wid  = threadIdx.x >> 6;
  __shared__ int ws[4];
  if (b < NRB) {
    int row = b * 256 + threadIdx.x;
    int s = 0;
    if (row < NN) {
#pragma unroll 8
      for (int g = 0; g < GG; ++g) s += gcnt[(size_t)g * NN + row];
      degi[row] = s;
    }
    int x = s;
#pragma unroll
    for (int d = 1; d < 64; d <<= 1) x += __shfl_xor(x, d, 64);
    if (lane == 0) ws[wid] = x;
    __syncthreads();
    if (threadIdx.x == 0) rpart[b] = ws[0] + ws[1] + ws[2] + ws[3];
  } else {
    int q = b - NRB;
    if (q >= 27) return;
    int s = 0;
    for (int c = threadIdx.x; c < NCHUNK; c += 256) s += bh[q * NCHUNK + c];
    int x = s;
#pragma unroll
    for (int d = 1; d < 64; d <<= 1) x += __shfl_xor(x, d, 64);
    if (lane == 0) ws[wid] = x;
    __syncthreads();
    if (threadIdx.x == 0) btot[q] = ws[0] + ws[1] + ws[2] + ws[3];
  }
}

// ---------------------------------------------------------------------------
// scan_tiny (1 block, 256 thr): Hillis-Steele exclusive scans in LDS:
// rpart[196] -> rpartx, btot[27] -> bstart (+bstart[27]=EE).
// ---------------------------------------------------------------------------
__global__ __launch_bounds__(256) void scan_tiny(const int* __restrict__ rpart,
                                                 const int* __restrict__ btot,
                                                 int* __restrict__ rpartx,
                                                 int* __restrict__ bstart) {
  __shared__ int sA[256];
  __shared__ int sB[32];
  const int t = threadIdx.x;
  int origA = (t < NRB) ? rpart[t] : 0;
  sA[t] = origA;
  int origB = 0;
  if (t < 32) { origB = (t < 27) ? btot[t] : 0; sB[t] = origB; }
  __syncthreads();
#pragma unroll
  for (int d = 1; d < 256; d <<= 1) {
    int a = (t >= d) ? sA[t - d] : 0;
    int bb = (t < 32 && d < 32 && t >= d) ? sB[t - d] : 0;
    __syncthreads();
    sA[t] += a;
    if (t < 32 && d < 32) sB[t] += bb;
    __syncthreads();
  }
  if (t < NRB) rpartx[t] = sA[t] - origA;          // exclusive
  if (t < 27)  bstart[t] = sB[t] - origB;
  if (t == 27) bstart[27] = EE;
}

// ---------------------------------------------------------------------------
// scan_p3 (223 blocks): blocks [0,196): rstart[row] = rpartx[b] +
// block-exclusive-scan(degi within 256-row chunk) (barrier-light, no loop).
// Blocks [196,223): bh[q][c] = bstart[q] + within-bucket chunk prefix
// (7 sub-iterations of 256). Values identical to old scan_combo output.
// ---------------------------------------------------------------------------
__global__ __launch_bounds__(256) void scan_p3(int* __restrict__ bh,
                                               const int* __restrict__ degi,
                                               const int* __restrict__ rpartx,
                                               const int* __restrict__ bstart,
                                               int* __restrict__ rstart) {
  const int b = blockIdx.x;
  const int lane = threadIdx.x & 63;
  const int wid  = threadIdx.x >> 6;
  __shared__ int wsum[4];
  __shared__ int ctot;
  if (b < NRB) {
    int row = b * 256 + threadIdx.x;
    int v = (row < NN) ? degi[row] : 0;
    int x = v;
#pragma unroll
    for (int d = 1; d < 64; d <<= 1) {
      int y = __shfl_up(x, d, 64);
      if (lane >= d) x += y;
    }
    if (lane == 63) wsum[wid] = x;
    __syncthreads();
    int off = 0;
#pragma unroll
    for (int w = 0; w < 4; ++w) if (w < wid) off += wsum[w];
    if (row < NN) rstart[row] = rpartx[b] + off + (x - v);
    if (b == 0 && threadIdx.x == 0) rstart[NN] = EE;
  } else {
    int q = b - NRB;
    if (q >= 27) return;
    int carry = bstart[q];
    for (int c0 = 0; c0 < NCHUNK; c0 += 256) {
      int c = c0 + threadIdx.x;
      int v = (c < NCHUNK) ? bh[q * NCHUNK + c] : 0;
      int x = v;
#pragma unroll
      for (int d = 1; d < 64; d <<= 1) {
        int y = __shfl_up(x, d, 64);
        if (lane >= d) x += y;
      }
      if (lane == 63) wsum[wid] = x;
      __syncthreads();
      int off = 0;
#pragma unroll
      for (int w = 0; w < 4; ++w) if (w < wid) off += wsum[w];
      if (c < NCHUNK) bh[q * NCHUNK + c] = carry + off + (x - v);
      __syncthreads();                             // excl reads done
      if (threadIdx.x == 0) ctot = wsum[0] + wsum[1] + wsum[2] + wsum[3];
      __syncthreads();
      carry += ctot;                               // uniform across threads
    }
  }
}

// ---------------------------------------------------------------------------
// group_base: in-place gcnt[g][row] = rstart[row] + prefix over g'<g.
// Loads batched 8-wide so the 128-step chain isn't latency-serialized.
// ---------------------------------------------------------------------------
__global__ __launch_bounds__(256) void group_base(int* __restrict__ gcnt,
                                                  const int* __restrict__ rstart) {
  int row = blockIdx.x * 256 + threadIdx.x;
  if (row >= NN) return;
  int run = rstart[row];
  for (int g0 = 0; g0 < GG; g0 += 8) {
    int t[8];
#pragma unroll
    for (int j = 0; j < 8; ++j) t[j] = gcnt[(size_t)(g0 + j) * NN + row];
#pragma unroll
    for (int j = 0; j < 8; ++j) {
      int v = t[j];
      gcnt[(size_t)(g0 + j) * NN + row] = run;
      run += v;
    }
  }
}

// ---------------------------------------------------------------------------
// Counting-sort scatter, ZERO global atomics. 1 block = 1 chunk (same edge
// partitioning as prep's hist). Rank within (chunk,bin) via LDS atomics;
// base = pre-scanned bh[q*NCHUNK+c].
// edata PACKED 8 B: x = f0q | f1q<<16, y = f2q | col<<16  (frac unorm16,
// quantization err ~2e-5 in spline weights — verified R11/R12).
// rpos_arr[pos] = gcnt[e/GSZ][row] + lrank[e]   (row-sorted message slot).
// ---------------------------------------------------------------------------
static __device__ __forceinline__ unsigned q16(float fr) {
  return min((unsigned)(fr * 65536.0f), 65535u);
}
__global__ __launch_bounds__(256) void bucket_scatter(const float* __restrict__ pseudo,
                                                      const int* __restrict__ ei,
                                                      const unsigned short* __restrict__ lrank,
                                                      const int* __restrict__ gcnt,
                                                      const int* __restrict__ bh,
                                                      u32x2* __restrict__ edata,
                                                      int* __restrict__ rpos_arr) {
  __shared__ int lh[27];
  __shared__ int bb[27];
  if (threadIdx.x < 27) {
    lh[threadIdx.x] = 0;
    bb[threadIdx.x] = bh[threadIdx.x * NCHUNK + blockIdx.x];
  }
  __syncthreads();
  const int e0 = blockIdx.x * CH;
#pragma unroll
  for (int i = 0; i < CH / 256; ++i) {
    int e = e0 + i * 256 + threadIdx.x;
    if (e < EE) {
      float v0 = pseudo[e * 3 + 0] * 3.0f;
      float v1 = pseudo[e * 3 + 1] * 3.0f;
      float v2 = pseudo[e * 3 + 2] * 3.0f;
      float fb0 = fmaxf(fminf(floorf(v0), 2.0f), 0.0f);
      float fb1 = fmaxf(fminf(floorf(v1), 2.0f), 0.0f);
      float fb2 = fmaxf(fminf(floorf(v2), 2.0f), 0.0f);
      int q = (int)fb0 + 3 * (int)fb1 + 9 * (int)fb2;
      int rk = atomicAdd(&lh[q], 1);
      int pos = bb[q] + rk;
      int row = ei[e];
      int col = ei[EE + e];
      int ge  = e / GSZ;
      u32x2 pk;
      pk.x = q16(v0 - fb0) | (q16(v1 - fb1) << 16);
      pk.y = q16(v2 - fb2) | ((unsigned)col << 16);
      edata[pos] = pk;
      rpos_arr[pos] = gcnt[(size_t)ge * NN + row] + (int)lrank[e];
    }
  }
}

// ---------------------------------------------------------------------------
// Bucketed MFMA, atomic-free, SWAPPED OPERANDS, DEPTH-2 PIPELINE.
// Per group of 16 edges: D = mfma(A=W^T tile (VGPR frags), B=f^T (fbh), 0)
//   -> D[row=(l>>4)*4+r = o-channel][col=l&15 = edge]  (m89 layout).
// Lane l owns edge m=l&15; weights + rpos lane-local (no cross-lane ops).
// Pipeline: edata/rpos fetched TWO groups ahead; fbh gather ONE group ahead
// using an edata value that landed a full iteration earlier.
// Store: ONE dwordx4 per lane: msg4[rp*4+kq] = {pk(o,o+16)}_{r=0..3}.
// ---------------------------------------------------------------------------
__global__ __launch_bounds__(256) void edge_mfma_nw(const u32x2* __restrict__ edata,
                                                    const int* __restrict__ rpos_arr,
                                                    const short* __restrict__ fbh,
                                                    const short* __restrict__ Wb,
                                                    const int* __restrict__ bstart,
                                                    u32x4* __restrict__ msg4) {
  const int q   = blockIdx.x / BPB;
  const int sub = blockIdx.x % BPB;
  const int l   = threadIdx.x & 63;
  const int wid = threadIdx.x >> 6;

  const int start = bstart[q];
  const int end   = bstart[q + 1];
  const int nE    = end - start;
  if (nE <= 0) return;
  const int ngroups = (nE + 15) >> 4;

  const int b0 = q % 3, b1 = (q / 3) % 3, b2 = q / 9;
  const int base = b0 + 4 * b1 + 16 * b2;
  const int ko[8] = {0, 1, 4, 5, 16, 17, 20, 21};

  s16x8 bf[8][2];                                  // bucket's W frags, 64 VGPRs
#pragma unroll
  for (int s = 0; s < 8; ++s) {
    int kmat = base + ko[s];
#pragma unroll
    for (int oh = 0; oh < 2; ++oh)
      bf[s][oh] = ((const s16x8*)Wb)[(kmat * 2 + oh) * 64 + l];
  }

  const int m   = l & 15;         // edge-in-group OWNED by this lane
  const int kq  = l >> 4;         // B k-chunk / D o-quarter
  const int stride = BPB * 4;
  const float inv16 = 1.0f / 65536.0f;

  int gA = sub * 4 + wid;
  if (gA >= ngroups) return;
  int gB = gA + stride;

  // clamped indices (invalid -> start; garbage compute, store guarded)
  int iA = start + gA * 16 + m;  int ciA = iA < end ? iA : start;
  int iB = start + gB * 16 + m;  int ciB = (gB < ngroups && iB < end) ? iB : start;

  u32x2 edA = edata[ciA];  int rpA = rpos_arr[ciA];
  u32x2 edB = edata[ciB];  int rpB = rpos_arr[ciB];
  s16x8 afA = ((const s16x8*)fbh)[(size_t)(edA.y >> 16) * 4 + kq];

  while (true) {
    const bool moreB = gB < ngroups;
    const int gC = gB + stride;
    int iC = start + gC * 16 + m;
    int ciC = (gC < ngroups && iC < end) ? iC : start;
    u32x2 edC = edata[ciC];                        // depth-2 prefetch
    int   rpC = rpos_arr[ciC];
    // depth-1 fbh prefetch — edB landed a full iteration ago
    s16x8 afB = ((const s16x8*)fbh)[(size_t)(edB.y >> 16) * 4 + kq];

    // spline weights of this lane's OWN edge (unorm16 fracs)
    float f0 = (float)(edA.x & 0xFFFFu) * inv16;
    float f1 = (float)(edA.x >> 16)     * inv16;
    float f2 = (float)(edA.y & 0xFFFFu) * inv16;
    float g0 = 1.0f - f0, g1c = 1.0f - f1, g2c = 1.0f - f2;
    float w8[8];
    w8[0] = g0 * g1c * g2c; w8[1] = f0 * g1c * g2c;
    w8[2] = g0 * f1 * g2c;  w8[3] = f0 * f1 * g2c;
    w8[4] = g0 * g1c * f2;  w8[5] = f0 * g1c * f2;
    w8[6] = g0 * f1 * f2;   w8[7] = f0 * f1 * f2;

    f32x4 acc0 = {0.f, 0.f, 0.f, 0.f}, acc1 = {0.f, 0.f, 0.f, 0.f};
#pragma unroll
    for (int s = 0; s < 8; ++s) {
      f32x4 d0 = __builtin_amdgcn_mfma_f32_16x16x32_bf16(bf[s][0], afA,
                   (f32x4){0.f, 0.f, 0.f, 0.f}, 0, 0, 0);   // o = 0..15
      f32x4 d1 = __builtin_amdgcn_mfma_f32_16x16x32_bf16(bf[s][1], afA,
                   (f32x4){0.f, 0.f, 0.f, 0.f}, 0, 0, 0);   // o = 16..31
      float ws = w8[s];
#pragma unroll
      for (int r = 0; r < 4; ++r) {
        acc0[r] += ws * d0[r];
        acc1[r] += ws * d1[r];
      }
    }

    if (gA * 16 + m < nE) {                        // lane's own edge valid?
      u32x4 pk;
      pk.x = (unsigned)(unsigned short)f2bs(acc0[0]) |
             ((unsigned)(unsigned short)f2bs(acc1[0]) << 16);
      pk.y = (unsigned)(unsigned short)f2bs(acc0[1]) |
             ((unsigned)(unsigned short)f2bs(acc1[1]) << 16);
      pk.z = (unsigned)(unsigned short)f2bs(acc0[2]) |
             ((unsigned)(unsigned short)f2bs(acc1[2]) << 16);
      pk.w = (unsigned)(unsigned short)f2bs(acc0[3]) |
             ((unsigned)(unsigned short)f2bs(acc1[3]) << 16);
      msg4[(size_t)rpA * 4 + kq] = pk;             // one 16 B store per lane
    }

    if (!moreB) break;
    gA = gB; edA = edB; rpA = rpB; afA = afB;
    gB = gC; edB = edC; rpB = rpC;
  }
}

// ---------------------------------------------------------------------------
// Per-node gather: 16 lanes/node. Messages for node n are CONTIGUOUS slots
// [rstart[n], rstart[n+1]) -> fully coalesced stream. Sum bf16 in fp32,
// divide by deg, add bias. Lane j holds channels o=j and o=j+16.
// ---------------------------------------------------------------------------
__global__ __launch_bounds__(256) void gather_out(const unsigned* __restrict__ msg,
                                                  const int* __restrict__ rstart,
                                                  const float* __restrict__ bias,
                                                  float* __restrict__ out) {
  int n = (blockIdx.x * 256 + threadIdx.x) >> 4;   // node
  int j = threadIdx.x & 15;
  if (n >= NN) return;
  int s = rstart[n], e = rstart[n + 1];
  int cnt = e - s;
  const unsigned* mp = msg + (size_t)s * 16 + j;
  float s0 = 0.f, s1 = 0.f;
  int i = 0;
  for (; i + 4 <= cnt; i += 4) {                   // unroll-4 for MLP
    unsigned uA = mp[(size_t)(i + 0) * 16];
    unsigned uB = mp[(size_t)(i + 1) * 16];
    unsigned uC = mp[(size_t)(i + 2) * 16];
    unsigned uD = mp[(size_t)(i + 3) * 16];
    s0 += __uint_as_float(uA << 16); s1 += __uint_as_float(uA & 0xFFFF0000u);
    s0 += __uint_as_float(uB << 16); s1 += __uint_as_float(uB & 0xFFFF0000u);
    s0 += __uint_as_float(uC << 16); s1 += __uint_as_float(uC & 0xFFFF0000u);
    s0 += __uint_as_float(uD << 16); s1 += __uint_as_float(uD & 0xFFFF0000u);
  }
  for (; i < cnt; ++i) {
    unsigned u = mp[(size_t)i * 16];
    s0 += __uint_as_float(u << 16);
    s1 += __uint_as_float(u & 0xFFFF0000u);
  }
  float d = fmaxf((float)cnt, 1.0f);
  out[n * 32 + j]      = s0 / d + bias[j];
  out[n * 32 + 16 + j] = s1 / d + bias[16 + j];
}

// ---------------------------------------------------------------------------
// Fallback path (small workspace): direct per-edge compute + atomics.
// ---------------------------------------------------------------------------
static __device__ __forceinline__ void spline_basis(const float* __restrict__ pseudo,
                                                    int e, float w[8], int& base) {
  float v0 = pseudo[e * 3 + 0] * 3.0f;
  float v1 = pseudo[e * 3 + 1] * 3.0f;
  float v2 = pseudo[e * 3 + 2] * 3.0f;
  float b0 = fmaxf(fminf(floorf(v0), 2.0f), 0.0f);
  float b1 = fmaxf(fminf(floorf(v1), 2.0f), 0.0f);
  float b2 = fmaxf(fminf(floorf(v2), 2.0f), 0.0f);
  float f0 = v0 - b0, f1 = v1 - b1, f2 = v2 - b2;
  float g0 = 1.0f - f0, g1 = 1.0f - f1, g2 = 1.0f - f2;
  base = (int)b0 + 4 * (int)b1 + 16 * (int)b2;
  w[0] = g0 * g1 * g2; w[1] = f0 * g1 * g2;
  w[2] = g0 * f1 * g2; w[3] = f0 * f1 * g2;
  w[4] = g0 * g1 * f2; w[5] = f0 * g1 * f2;
  w[6] = g0 * f1 * f2; w[7] = f0 * f1 * f2;
}

__global__ __launch_bounds__(256) void edge_direct(const float* __restrict__ pseudo,
                                                   const int* __restrict__ ei,
                                                   const float* __restrict__ f,
                                                   const float* __restrict__ W,
                                                   float* __restrict__ acc,
                                                   float* __restrict__ deg) {
  const int tid = blockIdx.x * 256 + threadIdx.x;
  const int e = tid >> 5;
  const int o = tid & 31;
  if (e >= EE) return;
  const int row = ei[e];
  const int col = ei[EE + e];
  float w[8]; int base;
  spline_basis(pseudo, e, w, base);
  const float myf = f[col * 32 + o];
  float a = 0.0f;
  for (int i = 0; i < 32; ++i) {
    float fi = __shfl(myf, i, 32);
    float wsum = 0.0f;
#pragma unroll
    for (int s = 0; s < 8; ++s)
      wsum += w[s] * W[(size_t)(base + kOffs[s]) * 1024 + i * 32 + o];
    a += fi * wsum;
  }
  atomicAdd(acc + (size_t)row * 32 + o, a);
  if (o == 0) atomicAdd(deg + row, 1.0f);
}

__global__ __launch_bounds__(256) void finalize(const float* __restrict__ acc,
                                                const float* __restrict__ deg,
                                                const float* __restrict__ bias,
                                                float* __restrict__ out) {
  int tid = blockIdx.x * 256 + threadIdx.x;
  if (tid >= NN * 32) return;
  int n = tid >> 5, o = tid & 31;
  float d = fmaxf(deg[n], 1.0f);
  out[tid] = acc[tid] / d + bias[o];
}

extern "C" void kernel_launch(void* const* d_in, const int* in_sizes, int n_in,
                              void* d_out, int out_size, void* d_ws, size_t ws_size,
                              hipStream_t stream) {
  const float* f      = (const float*)d_in[0];
  const float* pseudo = (const float*)d_in[1];
  const float* W      = (const float*)d_in[2];
  const float* bias   = (const float*)d_in[3];
  const int*   ei     = (const int*)d_in[4];
  float* out = (float*)d_out;

  // Workspace layout (~154.3 MB total; no memset — all buffers fully written)
  constexpr size_t DEGI_OFF   = 0;                             // NN ints
  constexpr size_t RPART_OFF  = 200064;                        // 196 ints
  constexpr size_t BTOT_OFF   = 200960;                        // 27 ints
  constexpr size_t RPARTX_OFF = 201088;                        // 196 ints
  constexpr size_t BST_OFF    = 201984;                        // 28 ints
  constexpr size_t RST_OFF    = 202112;                        // NN+1 ints
  constexpr size_t BH_OFF     = 402176;                        // 27*NCHUNK ints
  constexpr size_t LRANK_OFF  = 571008;                        // EE u16
  constexpr size_t GCNT_OFF   = LRANK_OFF + (size_t)EE * 2;    //   3,771,008
  constexpr size_t ED_OFF     = GCNT_OFF + (size_t)GG * NN * 4;//  29,371,008
  constexpr size_t RPOS_OFF   = ED_OFF + (size_t)EE * 8;       //  42,171,008
  constexpr size_t MSG_OFF    = RPOS_OFF + (size_t)EE * 4;     //  48,571,008
  constexpr size_t FBH_OFF    = MSG_OFF + (size_t)EE * 64;     // 150,971,008
  constexpr size_t WB_OFF     = FBH_OFF + (size_t)NN * 64;     // 154,171,008
  constexpr size_t TOTAL      = WB_OFF + 128 * 64 * 8 * 2;     // 154,302,080

  char* ws = (char*)d_ws;

  if (ws_size >= TOTAL) {
    int*            degi   = (int*)(ws + DEGI_OFF);
    int*            rpart  = (int*)(ws + RPART_OFF);
    int*            btot   = (int*)(ws + BTOT_OFF);
    int*            rpartx = (int*)(ws + RPARTX_OFF);
    int*            bst    = (int*)(ws + BST_OFF);
    int*            rst    = (int*)(ws + RST_OFF);
    int*            bh     = (int*)(ws + BH_OFF);
    unsigned short* lrank  = (unsigned short*)(ws + LRANK_OFF);
    int*            gcnt   = (int*)(ws + GCNT_OFF);
    u32x2*          edata  = (u32x2*)(ws + ED_OFF);
    int*            rpos   = (int*)(ws + RPOS_OFF);
    u32x4*          msg4   = (u32x4*)(ws + MSG_OFF);
    unsigned*       msg    = (unsigned*)(ws + MSG_OFF);
    short*          fbh    = (short*)(ws + FBH_OFF);
    short*          Wb     = (short*)(ws + WB_OFF);

    group_rank<<<GG, 256, 0, stream>>>(ei, lrank, gcnt);
    prep<<<PREP_BLOCKS, 256, 0, stream>>>(W, f, pseudo, Wb, fbh, bh);
    sum_p1<<<NRB + 27, 256, 0, stream>>>(gcnt, bh, degi, rpart, btot);
    scan_tiny<<<1, 256, 0, stream>>>(rpart, btot, rpartx, bst);
    scan_p3<<<NRB + 27, 256, 0, stream>>>(bh, degi, rpartx, bst, rst);
    group_base<<<(NN + 255) / 256, 256, 0, stream>>>(gcnt, rst);
    bucket_scatter<<<NCHUNK, 256, 0, stream>>>(pseudo, ei, lrank, gcnt, bh, edata, rpos);
    edge_mfma_nw<<<27 * BPB, 256, 0, stream>>>(edata, rpos, fbh, Wb, bst, msg4);
    gather_out<<<(NN * 16 + 255) / 256, 256, 0, stream>>>(msg, rst, bias, out);
  } else {
    constexpr size_t ACC_SZ = (size_t)NN * 32 * 4;
    float* acc = (float*)ws;
    float* deg = (float*)(ws + ACC_SZ);
    hipMemsetAsync(acc, 0, ACC_SZ + (size_t)NN * 4, stream);
    edge_direct<<<(EE * 32) / 256, 256, 0, stream>>>(pseudo, ei, f, W, acc, deg);
    finalize<<<(NN * 32) / 256, 256, 0, stream>>>(acc, deg, bias, out);
  }
}

// Round 14
// 228.289 us; speedup vs baseline: 1.5588x; 1.1054x over previous
//
#include <hip/hip_runtime.h>
#include <hip/hip_bf16.h>

// Problem constants: N=50000, E=1600000, D=3, IN=32, OUT=32, KS=4, K=64, S=8
// R14: R13 (252.4 us) with launch-chain compression:
//   scan_tiny + scan_p3 + group_base fused into ONE kernel (scan_base):
//     each block redundantly scans rpart[196]/btot[27] in LDS (cheap),
//     row-blocks then compute rstart AND apply group_base to their rows;
//     bucket-blocks scan their bh row. 9 -> 7 kernel launches.
//   group_rank bumped to 512 threads (8 waves issuing the LDS-atomic chain).
// Everything else byte-identical to R13.
#define NN 50000
#define EE 1600000
#define BPB 96               // blocks per bucket in edge_mfma_nw
#define CH 1024              // edges per chunk (bucket hist/scatter)
#define NCHUNK ((EE + CH - 1) / CH)   // 1563
#define GG 128               // rank groups
#define GSZ (EE / GG)        // 12500 edges per group (exact)
#define NRB 196              // row blocks (ceil(NN/256))

typedef __attribute__((ext_vector_type(8))) short    s16x8;   // 8 bf16 (4 VGPRs)
typedef __attribute__((ext_vector_type(4))) float    f32x4;   // MFMA C/D frag
typedef __attribute__((ext_vector_type(2))) unsigned u32x2;   // 8 B packed edge
typedef __attribute__((ext_vector_type(4))) unsigned u32x4;   // 16 B msg store

static __device__ __forceinline__ short f2bs(float x) {
  __hip_bfloat16 h = __float2bfloat16(x);
  short s; __builtin_memcpy(&s, &h, 2); return s;
}

__constant__ int kOffs[8] = {0, 1, 4, 5, 16, 17, 20, 21};

// ---------------------------------------------------------------------------
// group_rank (512 thr): block g owns edges [g*GSZ,(g+1)*GSZ). Full-row
// histogram in LDS (2 rows/u32; halves never carry: per-half <= 12500).
// LDS atomic RETURN = within-(group,row) rank -> lrank[e].
// ---------------------------------------------------------------------------
__global__ __launch_bounds__(512) void group_rank(const int* __restrict__ ei,
                                                  unsigned short* __restrict__ lrank,
                                                  int* __restrict__ gcnt) {
  __shared__ unsigned lh32[NN / 2];                // 25000 words = 100 KB
  for (int j = threadIdx.x; j < NN / 2; j += 512) lh32[j] = 0;
  __syncthreads();
  const int g  = blockIdx.x;
  const int e0 = g * GSZ;
  for (int i = threadIdx.x; i < GSZ; i += 512) {
    int e = e0 + i;
    int row = ei[e];
    unsigned add = (row & 1) ? 0x10000u : 1u;
    unsigned ret = atomicAdd(&lh32[row >> 1], add);
    unsigned r = (row & 1) ? (ret >> 16) : (ret & 0xFFFFu);
    lrank[e] = (unsigned short)r;
  }
  __syncthreads();
  for (int j = threadIdx.x; j < NN / 2; j += 512) {
    unsigned u = lh32[j];
    gcnt[(size_t)g * NN + 2 * j]     = (int)(u & 0xFFFFu);
    gcnt[(size_t)g * NN + 2 * j + 1] = (int)(u >> 16);
  }
}

// ---------------------------------------------------------------------------
// prep (fused): blocks [0,32) conv_w ; [32,160) pack_f ; [160,160+NCHUNK)
// per-chunk 27-bin bucket histogram (LDS-only atomics).
// conv_w frag layout: (tile t=kmat*2+oh, lane l, j) =
//   W[kmat][(l>>4)*8+j][oh*16+(l&15)] — read as A-frag it is W^T.
// ---------------------------------------------------------------------------
#define PREP_BLOCKS (160 + NCHUNK)
__global__ __launch_bounds__(256) void prep(const float* __restrict__ W,
                                            const float* __restrict__ f,
                                            const float* __restrict__ pseudo,
                                            short* __restrict__ Wb,
                                            short* __restrict__ fbh,
                                            int* __restrict__ bh) {
  const int b = blockIdx.x;
  if (b < 32) {
    int tid = b * 256 + threadIdx.x;               // 8192 threads, one frag each
    int t = tid >> 6, l = tid & 63;
    int c = t * 16 + (l & 15);
    int k0 = (l >> 4) * 8;
    s16x8 frag;
#pragma unroll
    for (int j = 0; j < 8; ++j)
      frag[j] = f2bs(W[(c >> 5) * 1024 + (k0 + j) * 32 + (c & 31)]);
    ((s16x8*)Wb)[tid] = frag;
  } else if (b < 160) {
    for (int tid = (b - 32) * 256 + threadIdx.x; tid < NN * 32 / 8; tid += 128 * 256) {
      const f32x4* fp = (const f32x4*)f + (size_t)tid * 2;
      f32x4 a = fp[0], c = fp[1];
      s16x8 o;
#pragma unroll
      for (int j = 0; j < 4; ++j) { o[j] = f2bs(a[j]); o[4 + j] = f2bs(c[j]); }
      ((s16x8*)fbh)[tid] = o;
    }
  } else {
    __shared__ int lh[27];
    if (threadIdx.x < 27) lh[threadIdx.x] = 0;
    __syncthreads();
    const int c  = b - 160;                        // chunk id
    const int e0 = c * CH;
#pragma unroll
    for (int i = 0; i < CH / 256; ++i) {
      int e = e0 + i * 256 + threadIdx.x;
      if (e < EE) {
        float v0 = pseudo[e * 3 + 0] * 3.0f;
        float v1 = pseudo[e * 3 + 1] * 3.0f;
        float v2 = pseudo[e * 3 + 2] * 3.0f;
        int b0 = (int)fminf(fmaxf(floorf(v0), 0.0f), 2.0f);
        int b1 = (int)fminf(fmaxf(floorf(v1), 0.0f), 2.0f);
        int b2 = (int)fminf(fmaxf(floorf(v2), 0.0f), 2.0f);
        atomicAdd(&lh[b0 + 3 * b1 + 9 * b2], 1);
      }
    }
    __syncthreads();
    if (threadIdx.x < 27) bh[threadIdx.x * NCHUNK + c] = lh[threadIdx.x];
  }
}

// ---------------------------------------------------------------------------
// sum_p1 (223 blocks): blocks [0,196): degi[row] = sum_g gcnt[g][row]
// (coalesced per g) + block partial sum -> rpart[b].
// Blocks [196,223): btot[q] = sum_c bh[q][c].
// ---------------------------------------------------------------------------
__global__ __launch_bounds__(256) void sum_p1(const int* __restrict__ gcnt,
                                              const int* __restrict__ bh,
                                              int* __restrict__ degi,
                                              int* __restrict__ rpart,
                                              int* __restrict__ btot) {
  const int b = blockIdx.x;
  const int lane = threadIdx.x & 63;
  const int wid  = threadIdx.x >> 6;
  __shared__ int ws[4];
  if (b < NRB) {
    int row = b * 256 + threadIdx.x;
    int s = 0;
    if (row < NN) {
#pragma unroll 8
      for (int g = 0; g < GG; ++g) s += gcnt[(size_t)g * NN + row];
      degi[row] = s;
    }
    int x = s;
#pragma unroll
    for (int d = 1; d < 64; d <<= 1) x += __shfl_xor(x, d, 64);
    if (lane == 0) ws[wid] = x;
    __syncthreads();
    if (threadIdx.x == 0) rpart[b] = ws[0] + ws[1] + ws[2] + ws[3];
  } else {
    int q = b - NRB;
    if (q >= 27) return;
    int s = 0;
    for (int c = threadIdx.x; c < NCHUNK; c += 256) s += bh[q * NCHUNK + c];
    int x = s;
#pragma unroll
    for (int d = 1; d < 64; d <<= 1) x += __shfl_xor(x, d, 64);
    if (lane == 0) ws[wid] = x;
    __syncthreads();
    if (threadIdx.x == 0) btot[q] = ws[0] + ws[1] + ws[2] + ws[3];
  }
}

// ---------------------------------------------------------------------------
// scan_base (223 blocks) — fuses scan_tiny + scan_p3 + group_base:
// Every block redundantly scans the tiny partial arrays in LDS (8 HS steps).
// Blocks [0,196): rstart[row] = excl(rpart)[b] + block-excl-scan(degi);
//   then IMMEDIATELY group_base for own rows (gcnt[g][row] -> running base).
// Blocks [196,223): q=b-196: bh[q][c] = excl(btot)[q] + within-row prefix;
//   block q==0 also writes bstart[0..27] (for edge_mfma).
// Output values identical to R13's scan_tiny+scan_p3+group_base.
// ---------------------------------------------------------------------------
__global__ __launch_bounds__(256) void scan_base(int* __restrict__ bh,
                                                 const int* __restrict__ degi,
                                                 const int* __restrict__ rpart,
                                                 const int* __restrict__ btot,
                                                 int* __restrict__ gcnt,
                                                 int* __restrict__ rstart,
                                                 int* __restrict__ bstart) {
  const int b = blockIdx.x;
  const int t = threadIdx.x;
  const int lane = t & 63;
  const int wid  = t >> 6;
  __shared__ int sA[256];
  __shared__ int sbst[28];
  __shared__ int wsum[4];
  __shared__ int ctot;
  if (b < NRB) {
    // in-block inclusive scan of rpart[196]
    int v = (t < NRB) ? rpart[t] : 0;
    sA[t] = v;
    __syncthreads();
#pragma unroll
    for (int d = 1; d < 256; d <<= 1) {
      int a = (t >= d) ? sA[t - d] : 0;
      __syncthreads();
      sA[t] += a;
      __syncthreads();
    }
    int rbase = (b == 0) ? 0 : sA[b - 1];          // exclusive at b
    int row = b * 256 + t;
    int dv = (row < NN) ? degi[row] : 0;
    int x = dv;
#pragma unroll
    for (int d = 1; d < 64; d <<= 1) {
      int y = __shfl_up(x, d, 64);
      if (lane >= d) x += y;
    }
    if (lane == 63) wsum[wid] = x;
    __syncthreads();
    int off = 0;
#pragma unroll
    for (int w = 0; w < 4; ++w) if (w < wid) off += wsum[w];
    int rv = rbase + off + (x - dv);
    if (row < NN) rstart[row] = rv;
    if (b == 0 && t == 0) rstart[NN] = EE;
    // group_base fused: gcnt[g][row] = rv + prefix over g'<g (batched 8-wide)
    if (row < NN) {
      int run = rv;
      for (int g0 = 0; g0 < GG; g0 += 8) {
        int tb[8];
#pragma unroll
        for (int j = 0; j < 8; ++j) tb[j] = gcnt[(size_t)(g0 + j) * NN + row];
#pragma unroll
        for (int j = 0; j < 8; ++j) {
          int vv = tb[j];
          gcnt[(size_t)(g0 + j) * NN + row] = run;
          run += vv;
        }
      }
    }
  } else {
    int q = b - NRB;                               // 0..26
    // in-block exclusive scan of btot[27] (wave 0)
    if (t < 64) {
      int v = (lane < 27) ? btot[lane] : 0;
      int x = v;
#pragma unroll
      for (int d = 1; d < 32; d <<= 1) {
        int y = __shfl_up(x, d, 64);
        if (lane >= d) x += y;
      }
      if (lane < 27) sbst[lane] = x - v;           // exclusive
      if (lane == 26) sbst[27] = x;                // total = EE
    }
    __syncthreads();
    if (q == 0 && t < 28) bstart[t] = sbst[t];     // publish for edge_mfma
    int carry = sbst[q];
    for (int c0 = 0; c0 < NCHUNK; c0 += 256) {
      int c = c0 + t;
      int v = (c < NCHUNK) ? bh[q * NCHUNK + c] : 0;
      int x = v;
#pragma unroll
      for (int d = 1; d < 64; d <<= 1) {
        int y = __shfl_up(x, d, 64);
        if (lane >= d) x += y;
      }
      if (lane == 63) wsum[wid] = x;
      __syncthreads();
      int off = 0;
#pragma unroll
      for (int w = 0; w < 4; ++w) if (w < wid) off += wsum[w];
      if (c < NCHUNK) bh[q * NCHUNK + c] = carry + off + (x - v);
      __syncthreads();                             // excl reads done
      if (t == 0) ctot = wsum[0] + wsum[1] + wsum[2] + wsum[3];
      __syncthreads();
      carry += ctot;                               // uniform across threads
    }
  }
}

// ---------------------------------------------------------------------------
// Counting-sort scatter, ZERO global atomics. 1 block = 1 chunk (same edge
// partitioning as prep's hist). Rank within (chunk,bin) via LDS atomics;
// base = pre-scanned bh[q*NCHUNK+c].
// edata PACKED 8 B: x = f0q | f1q<<16, y = f2q | col<<16  (frac unorm16,
// quantization err ~2e-5 in spline weights — verified R11/R12/R13).
// rpos_arr[pos] = gcnt[e/GSZ][row] + lrank[e]   (row-sorted message slot).
// ---------------------------------------------------------------------------
static __device__ __forceinline__ unsigned q16(float fr) {
  return min((unsigned)(fr * 65536.0f), 65535u);
}
__global__ __launch_bounds__(256) void bucket_scatter(const float* __restrict__ pseudo,
                                                      const int* __restrict__ ei,
                                                      const unsigned short* __restrict__ lrank,
                                                      const int* __restrict__ gcnt,
                                                      const int* __restrict__ bh,
                                                      u32x2* __restrict__ edata,
                                                      int* __restrict__ rpos_arr) {
  __shared__ int lh[27];
  __shared__ int bb[27];
  if (threadIdx.x < 27) {
    lh[threadIdx.x] = 0;
    bb[threadIdx.x] = bh[threadIdx.x * NCHUNK + blockIdx.x];
  }
  __syncthreads();
  const int e0 = blockIdx.x * CH;
#pragma unroll
  for (int i = 0; i < CH / 256; ++i) {
    int e = e0 + i * 256 + threadIdx.x;
    if (e < EE) {
      float v0 = pseudo[e * 3 + 0] * 3.0f;
      float v1 = pseudo[e * 3 + 1] * 3.0f;
      float v2 = pseudo[e * 3 + 2] * 3.0f;
      float fb0 = fmaxf(fminf(floorf(v0), 2.0f), 0.0f);
      float fb1 = fmaxf(fminf(floorf(v1), 2.0f), 0.0f);
      float fb2 = fmaxf(fminf(floorf(v2), 2.0f), 0.0f);
      int q = (int)fb0 + 3 * (int)fb1 + 9 * (int)fb2;
      int rk = atomicAdd(&lh[q], 1);
      int pos = bb[q] + rk;
      int row = ei[e];
      int col = ei[EE + e];
      int ge  = e / GSZ;
      u32x2 pk;
      pk.x = q16(v0 - fb0) | (q16(v1 - fb1) << 16);
      pk.y = q16(v2 - fb2) | ((unsigned)col << 16);
      edata[pos] = pk;
      rpos_arr[pos] = gcnt[(size_t)ge * NN + row] + (int)lrank[e];
    }
  }
}

// ---------------------------------------------------------------------------
// Bucketed MFMA, atomic-free, SWAPPED OPERANDS, DEPTH-2 PIPELINE.
// Per group of 16 edges: D = mfma(A=W^T tile (VGPR frags), B=f^T (fbh), 0)
//   -> D[row=(l>>4)*4+r = o-channel][col=l&15 = edge]  (m89 layout).
// Lane l owns edge m=l&15; weights + rpos lane-local (no cross-lane ops).
// Pipeline: edata/rpos fetched TWO groups ahead; fbh gather ONE group ahead
// using an edata value that landed a full iteration earlier.
// Store: ONE dwordx4 per lane: msg4[rp*4+kq] = {pk(o,o+16)}_{r=0..3}.
// ---------------------------------------------------------------------------
__global__ __launch_bounds__(256) void edge_mfma_nw(const u32x2* __restrict__ edata,
                                                    const int* __restrict__ rpos_arr,
                                                    const short* __restrict__ fbh,
                                                    const short* __restrict__ Wb,
                                                    const int* __restrict__ bstart,
                                                    u32x4* __restrict__ msg4) {
  const int q   = blockIdx.x / BPB;
  const int sub = blockIdx.x % BPB;
  const int l   = threadIdx.x & 63;
  const int wid = threadIdx.x >> 6;

  const int start = bstart[q];
  const int end   = bstart[q + 1];
  const int nE    = end - start;
  if (nE <= 0) return;
  const int ngroups = (nE + 15) >> 4;

  const int b0 = q % 3, b1 = (q / 3) % 3, b2 = q / 9;
  const int base = b0 + 4 * b1 + 16 * b2;
  const int ko[8] = {0, 1, 4, 5, 16, 17, 20, 21};

  s16x8 bf[8][2];                                  // bucket's W frags, 64 VGPRs
#pragma unroll
  for (int s = 0; s < 8; ++s) {
    int kmat = base + ko[s];
#pragma unroll
    for (int oh = 0; oh < 2; ++oh)
      bf[s][oh] = ((const s16x8*)Wb)[(kmat * 2 + oh) * 64 + l];
  }

  const int m   = l & 15;         // edge-in-group OWNED by this lane
  const int kq  = l >> 4;         // B k-chunk / D o-quarter
  const int stride = BPB * 4;
  const float inv16 = 1.0f / 65536.0f;

  int gA = sub * 4 + wid;
  if (gA >= ngroups) return;
  int gB = gA + stride;

  // clamped indices (invalid -> start; garbage compute, store guarded)
  int iA = start + gA * 16 + m;  int ciA = iA < end ? iA : start;
  int iB = start + gB * 16 + m;  int ciB = (gB < ngroups && iB < end) ? iB : start;

  u32x2 edA = edata[ciA];  int rpA = rpos_arr[ciA];
  u32x2 edB = edata[ciB];  int rpB = rpos_arr[ciB];
  s16x8 afA = ((const s16x8*)fbh)[(size_t)(edA.y >> 16) * 4 + kq];

  while (true) {
    const bool moreB = gB < ngroups;
    const int gC = gB + stride;
    int iC = start + gC * 16 + m;
    int ciC = (gC < ngroups && iC < end) ? iC : start;
    u32x2 edC = edata[ciC];                        // depth-2 prefetch
    int   rpC = rpos_arr[ciC];
    // depth-1 fbh prefetch — edB landed a full iteration ago
    s16x8 afB = ((const s16x8*)fbh)[(size_t)(edB.y >> 16) * 4 + kq];

    // spline weights of this lane's OWN edge (unorm16 fracs)
    float f0 = (float)(edA.x & 0xFFFFu) * inv16;
    float f1 = (float)(edA.x >> 16)     * inv16;
    float f2 = (float)(edA.y & 0xFFFFu) * inv16;
    float g0 = 1.0f - f0, g1c = 1.0f - f1, g2c = 1.0f - f2;
    float w8[8];
    w8[0] = g0 * g1c * g2c; w8[1] = f0 * g1c * g2c;
    w8[2] = g0 * f1 * g2c;  w8[3] = f0 * f1 * g2c;
    w8[4] = g0 * g1c * f2;  w8[5] = f0 * g1c * f2;
    w8[6] = g0 * f1 * f2;   w8[7] = f0 * f1 * f2;

    f32x4 acc0 = {0.f, 0.f, 0.f, 0.f}, acc1 = {0.f, 0.f, 0.f, 0.f};
#pragma unroll
    for (int s = 0; s < 8; ++s) {
      f32x4 d0 = __builtin_amdgcn_mfma_f32_16x16x32_bf16(bf[s][0], afA,
                   (f32x4){0.f, 0.f, 0.f, 0.f}, 0, 0, 0);   // o = 0..15
      f32x4 d1 = __builtin_amdgcn_mfma_f32_16x16x32_bf16(bf[s][1], afA,
                   (f32x4){0.f, 0.f, 0.f, 0.f}, 0, 0, 0);   // o = 16..31
      float ws = w8[s];
#pragma unroll
      for (int r = 0; r < 4; ++r) {
        acc0[r] += ws * d0[r];
        acc1[r] += ws * d1[r];
      }
    }

    if (gA * 16 + m < nE) {                        // lane's own edge valid?
      u32x4 pk;
      pk.x = (unsigned)(unsigned short)f2bs(acc0[0]) |
             ((unsigned)(unsigned short)f2bs(acc1[0]) << 16);
      pk.y = (unsigned)(unsigned short)f2bs(acc0[1]) |
             ((unsigned)(unsigned short)f2bs(acc1[1]) << 16);
      pk.z = (unsigned)(unsigned short)f2bs(acc0[2]) |
             ((unsigned)(unsigned short)f2bs(acc1[2]) << 16);
      pk.w = (unsigned)(unsigned short)f2bs(acc0[3]) |
             ((unsigned)(unsigned short)f2bs(acc1[3]) << 16);
      msg4[(size_t)rpA * 4 + kq] = pk;             // one 16 B store per lane
    }

    if (!moreB) break;
    gA = gB; edA = edB; rpA = rpB; afA = afB;
    gB = gC; edB = edC; rpB = rpC;
  }
}

// ---------------------------------------------------------------------------
// Per-node gather: 16 lanes/node. Messages for node n are CONTIGUOUS slots
// [rstart[n], rstart[n+1]) -> fully coalesced stream. Sum bf16 in fp32,
// divide by deg, add bias. Lane j holds channels o=j and o=j+16.
// ---------------------------------------------------------------------------
__global__ __launch_bounds__(256) void gather_out(const unsigned* __restrict__ msg,
                                                  const int* __restrict__ rstart,
                                                  const float* __restrict__ bias,
                                                  float* __restrict__ out) {
  int n = (blockIdx.x * 256 + threadIdx.x) >> 4;   // node
  int j = threadIdx.x & 15;
  if (n >= NN) return;
  int s = rstart[n], e = rstart[n + 1];
  int cnt = e - s;
  const unsigned* mp = msg + (size_t)s * 16 + j;
  float s0 = 0.f, s1 = 0.f;
  int i = 0;
  for (; i + 4 <= cnt; i += 4) {                   // unroll-4 for MLP
    unsigned uA = mp[(size_t)(i + 0) * 16];
    unsigned uB = mp[(size_t)(i + 1) * 16];
    unsigned uC = mp[(size_t)(i + 2) * 16];
    unsigned uD = mp[(size_t)(i + 3) * 16];
    s0 += __uint_as_float(uA << 16); s1 += __uint_as_float(uA & 0xFFFF0000u);
    s0 += __uint_as_float(uB << 16); s1 += __uint_as_float(uB & 0xFFFF0000u);
    s0 += __uint_as_float(uC << 16); s1 += __uint_as_float(uC & 0xFFFF0000u);
    s0 += __uint_as_float(uD << 16); s1 += __uint_as_float(uD & 0xFFFF0000u);
  }
  for (; i < cnt; ++i) {
    unsigned u = mp[(size_t)i * 16];
    s0 += __uint_as_float(u << 16);
    s1 += __uint_as_float(u & 0xFFFF0000u);
  }
  float d = fmaxf((float)cnt, 1.0f);
  out[n * 32 + j]      = s0 / d + bias[j];
  out[n * 32 + 16 + j] = s1 / d + bias[16 + j];
}

// ---------------------------------------------------------------------------
// Fallback path (small workspace): direct per-edge compute + atomics.
// ---------------------------------------------------------------------------
static __device__ __forceinline__ void spline_basis(const float* __restrict__ pseudo,
                                                    int e, float w[8], int& base) {
  float v0 = pseudo[e * 3 + 0] * 3.0f;
  float v1 = pseudo[e * 3 + 1] * 3.0f;
  float v2 = pseudo[e * 3 + 2] * 3.0f;
  float b0 = fmaxf(fminf(floorf(v0), 2.0f), 0.0f);
  float b1 = fmaxf(fminf(floorf(v1), 2.0f), 0.0f);
  float b2 = fmaxf(fminf(floorf(v2), 2.0f), 0.0f);
  float f0 = v0 - b0, f1 = v1 - b1, f2 = v2 - b2;
  float g0 = 1.0f - f0, g1 = 1.0f - f1, g2 = 1.0f - f2;
  base = (int)b0 + 4 * (int)b1 + 16 * (int)b2;
  w[0] = g0 * g1 * g2; w[1] = f0 * g1 * g2;
  w[2] = g0 * f1 * g2; w[3] = f0 * f1 * g2;
  w[4] = g0 * g1 * f2; w[5] = f0 * g1 * f2;
  w[6] = g0 * f1 * f2; w[7] = f0 * f1 * f2;
}

__global__ __launch_bounds__(256) void edge_direct(const float* __restrict__ pseudo,
                                                   const int* __restrict__ ei,
                                                   const float* __restrict__ f,
                                                   const float* __restrict__ W,
                                                   float* __restrict__ acc,
                                                   float* __restrict__ deg) {
  const int tid = blockIdx.x * 256 + threadIdx.x;
  const int e = tid >> 5;
  const int o = tid & 31;
  if (e >= EE) return;
  const int row = ei[e];
  const int col = ei[EE + e];
  float w[8]; int base;
  spline_basis(pseudo, e, w, base);
  const float myf = f[col * 32 + o];
  float a = 0.0f;
  for (int i = 0; i < 32; ++i) {
    float fi = __shfl(myf, i, 32);
    float wsum = 0.0f;
#pragma unroll
    for (int s = 0; s < 8; ++s)
      wsum += w[s] * W[(size_t)(base + kOffs[s]) * 1024 + i * 32 + o];
    a += fi * wsum;
  }
  atomicAdd(acc + (size_t)row * 32 + o, a);
  if (o == 0) atomicAdd(deg + row, 1.0f);
}

__global__ __launch_bounds__(256) void finalize(const float* __restrict__ acc,
                                                const float* __restrict__ deg,
                                                const float* __restrict__ bias,
                                                float* __restrict__ out) {
  int tid = blockIdx.x * 256 + threadIdx.x;
  if (tid >= NN * 32) return;
  int n = tid >> 5, o = tid & 31;
  float d = fmaxf(deg[n], 1.0f);
  out[tid] = acc[tid] / d + bias[o];
}

extern "C" void kernel_launch(void* const* d_in, const int* in_sizes, int n_in,
                              void* d_out, int out_size, void* d_ws, size_t ws_size,
                              hipStream_t stream) {
  const float* f      = (const float*)d_in[0];
  const float* pseudo = (const float*)d_in[1];
  const float* W      = (const float*)d_in[2];
  const float* bias   = (const float*)d_in[3];
  const int*   ei     = (const int*)d_in[4];
  float* out = (float*)d_out;

  // Workspace layout (~154.3 MB total; no memset — all buffers fully written)
  constexpr size_t DEGI_OFF   = 0;                             // NN ints
  constexpr size_t RPART_OFF  = 200064;                        // 196 ints
  constexpr size_t BTOT_OFF   = 200960;                        // 27 ints
  constexpr size_t BST_OFF    = 201984;                        // 28 ints
  constexpr size_t RST_OFF    = 202112;                        // NN+1 ints
  constexpr size_t BH_OFF     = 402176;                        // 27*NCHUNK ints
  constexpr size_t LRANK_OFF  = 571008;                        // EE u16
  constexpr size_t GCNT_OFF   = LRANK_OFF + (size_t)EE * 2;    //   3,771,008
  constexpr size_t ED_OFF     = GCNT_OFF + (size_t)GG * NN * 4;//  29,371,008
  constexpr size_t RPOS_OFF   = ED_OFF + (size_t)EE * 8;       //  42,171,008
  constexpr size_t MSG_OFF    = RPOS_OFF + (size_t)EE * 4;     //  48,571,008
  constexpr size_t FBH_OFF    = MSG_OFF + (size_t)EE * 64;     // 150,971,008
  constexpr size_t WB_OFF     = FBH_OFF + (size_t)NN * 64;     // 154,171,008
  constexpr size_t TOTAL      = WB_OFF + 128 * 64 * 8 * 2;     // 154,302,080

  char* ws = (char*)d_ws;

  if (ws_size >= TOTAL) {
    int*            degi   = (int*)(ws + DEGI_OFF);
    int*            rpart  = (int*)(ws + RPART_OFF);
    int*            btot   = (int*)(ws + BTOT_OFF);
    int*            bst    = (int*)(ws + BST_OFF);
    int*            rst    = (int*)(ws + RST_OFF);
    int*            bh     = (int*)(ws + BH_OFF);
    unsigned short* lrank  = (unsigned short*)(ws + LRANK_OFF);
    int*            gcnt   = (int*)(ws + GCNT_OFF);
    u32x2*          edata  = (u32x2*)(ws + ED_OFF);
    int*            rpos   = (int*)(ws + RPOS_OFF);
    u32x4*          msg4   = (u32x4*)(ws + MSG_OFF);
    unsigned*       msg    = (unsigned*)(ws + MSG_OFF);
    short*          fbh    = (short*)(ws + FBH_OFF);
    short*          Wb     = (short*)(ws + WB_OFF);

    group_rank<<<GG, 512, 0, stream>>>(ei, lrank, gcnt);
    prep<<<PREP_BLOCKS, 256, 0, stream>>>(W, f, pseudo, Wb, fbh, bh);
    sum_p1<<<NRB + 27, 256, 0, stream>>>(gcnt, bh, degi, rpart, btot);
    scan_base<<<NRB + 27, 256, 0, stream>>>(bh, degi, rpart, btot, gcnt, rst, bst);
    bucket_scatter<<<NCHUNK, 256, 0, stream>>>(pseudo, ei, lrank, gcnt, bh, edata, rpos);
    edge_mfma_nw<<<27 * BPB, 256, 0, stream>>>(edata, rpos, fbh, Wb, bst, msg4);
    gather_out<<<(NN * 16 + 255) / 256, 256, 0, stream>>>(msg, rst, bias, out);
  } else {
    constexpr size_t ACC_SZ = (size_t)NN * 32 * 4;
    float* acc = (float*)ws;
    float* deg = (float*)(ws + ACC_SZ);
    hipMemsetAsync(acc, 0, ACC_SZ + (size_t)NN * 4, stream);
    edge_direct<<<(EE * 32) / 256, 256, 0, stream>>>(pseudo, ei, f, W, acc, deg);
    finalize<<<(NN * 32) / 256, 256, 0, stream>>>(acc, deg, bias, out);
  }
}